// Round 1
// baseline (407.680 us; speedup 1.0000x reference)
//
#include <hip/hip_runtime.h>

// LatentMixer on MI355X. bf16-MFMA pipeline with runtime input-dtype sniffing.
// B=8, C=512, HW=4096, L=16, heads=8, d=64, scale=0.125, eps=1e-12.

typedef __bf16 bf16x8 __attribute__((ext_vector_type(8)));
typedef float floatx4 __attribute__((ext_vector_type(4)));
typedef short short8_t __attribute__((ext_vector_type(8)));

#define DEV __device__ __forceinline__

DEV float bf2f(unsigned short u){ union{unsigned int i; float f;} v; v.i = ((unsigned int)u)<<16; return v.f; }
DEV unsigned short f2bf(float f){
  union{float f; unsigned int i;} v; v.f = f;
  unsigned int i = v.i;
  return (unsigned short)((i + 0x7fffu + ((i>>16)&1u)) >> 16);
}

// ---------------- workspace layout (bytes) ----------------
#define OFF_XT     256ull                          // xT bf16 [8][4096][512]
#define OFF_KVX    (OFF_XT + 33554432ull)          // kvx bf16 [8][1024][4096]; later reused as xw bf16 [8][4096][512]
#define OFF_WKVX   (OFF_KVX + 67108864ull)         // w_kv_x bf16
#define OFF_WQX    (OFF_WKVX + 1048576ull)         // w_q_x bf16
#define OFF_WKVL   (OFF_WQX + 524288ull)           // w_kv_lat bf16
#define OFF_WPROJ  (OFF_WKVL + 1048576ull)         // w_proj bf16
#define OFF_WQLAT  (OFF_WPROJ + 524288ull)         // w_q_lat bf16
#define OFF_LATF   (OFF_WQLAT + 524288ull)         // latents f32 [512][16]
#define OFF_BIAS   (OFF_LATF + 32768ull)           // bias f32 [512]
#define OFF_QL     (OFF_BIAS + 4096ull)            // ql f32 [512][16]
#define OFF_QLH    (OFF_QL + 32768ull)             // ql-hat f32 [8][64][16]
#define OFF_GNUM   (OFF_QLH + 32768ull)            // attn1 numerator f32 [b][h][l][64]
#define OFF_GDEN   (OFF_GNUM + 524288ull)          // attn1 denominator f32 [b][h][l]
#define OFF_KVL    (OFF_GDEN + 4096ull)            // kvl f32 [b][1024][16]
#define OFF_KHAT   (OFF_KVL + 524288ull)           // k-hat f32 [b][h][l][64]
#define OFF_GVL    (OFF_KHAT + 524288ull)          // vl f32 [b][h][l][64]

// ---------------- dtype sniff ----------------
// If input is fp32, the low-mantissa shorts interpreted as bf16 have random
// exponent fields (max ~255 over 4096 samples). Genuine bf16 N(0,1) stays <=~130.
__global__ void k_sniff(const unsigned short* __restrict__ x, int* flag){
  int t = threadIdx.x;
  int m = 0;
  for (int i = t; i < 4096; i += 256){ int e = (x[i]>>7)&0xFF; m = (e>m)?e:m; }
  __shared__ int red[256];
  red[t] = m; __syncthreads();
  for (int s = 128; s > 0; s >>= 1){ if (t < s) red[t] = (red[t+s]>red[t])?red[t+s]:red[t]; __syncthreads(); }
  if (t == 0) flag[0] = (red[0] > 150) ? 1 : 0;   // 1 => fp32 inputs, 0 => bf16 inputs
}

// convert (or copy) a weight array to bf16
__global__ __launch_bounds__(256) void k_cvt(const void* __restrict__ src, unsigned short* __restrict__ dst,
                                             int n, const int* __restrict__ flag){
  int base = (blockIdx.x*256 + threadIdx.x)*8;
  if (base >= n) return;
  if (*flag){
    const float* s = (const float*)src + base;
    float4 v0 = *(const float4*)(s);
    float4 v1 = *(const float4*)(s+4);
    unsigned short tmp[8] __attribute__((aligned(16)));
    tmp[0]=f2bf(v0.x); tmp[1]=f2bf(v0.y); tmp[2]=f2bf(v0.z); tmp[3]=f2bf(v0.w);
    tmp[4]=f2bf(v1.x); tmp[5]=f2bf(v1.y); tmp[6]=f2bf(v1.z); tmp[7]=f2bf(v1.w);
    *(short8_t*)&dst[base] = *(short8_t*)tmp;
  } else {
    *(short8_t*)&dst[base] = *(const short8_t*)((const unsigned short*)src + base);
  }
}

// convert to f32 (latents, bias)
__global__ void k_cvtf(const void* __restrict__ src, float* __restrict__ dst, int n, const int* __restrict__ flag){
  int i = blockIdx.x*256 + threadIdx.x;
  if (i >= n) return;
  dst[i] = (*flag) ? ((const float*)src)[i] : bf2f(((const unsigned short*)src)[i]);
}

// ---------------- transpose x[b][c][n] -> xT[b][n][c] (bf16) ----------------
__global__ __launch_bounds__(256) void k_xt(const void* __restrict__ xraw, unsigned short* __restrict__ xT,
                                            const int* __restrict__ flag){
  int nb = blockIdx.x, cb = blockIdx.y, b = blockIdx.z;
  int n0 = nb*64, c0 = cb*64;
  __shared__ unsigned short tile[64][72];   // XOR-swizzled columns: col = n ^ (((row>>3)&7)<<3)
  int t = threadIdx.x;
  if (*flag){
    const float* xp = (const float*)xraw;
#pragma unroll
    for (int i = 0; i < 4; ++i){
      int ch = i*256 + t; int c = ch>>4, n4 = (ch&15)*4;
      float4 v = *(const float4*)&xp[((size_t)(b*512 + c0 + c))*4096 + n0 + n4];
      int cc = n4 ^ (((c>>3)&7)<<3);
      tile[c][cc+0]=f2bf(v.x); tile[c][cc+1]=f2bf(v.y); tile[c][cc+2]=f2bf(v.z); tile[c][cc+3]=f2bf(v.w);
    }
  } else {
    const unsigned short* xp = (const unsigned short*)xraw;
#pragma unroll
    for (int i = 0; i < 2; ++i){
      int ch = i*256 + t; int c = ch>>3, n8 = (ch&7)*8;
      *(short8_t*)&tile[c][n8 ^ (((c>>3)&7)<<3)] =
        *(const short8_t*)&xp[((size_t)(b*512 + c0 + c))*4096 + n0 + n8];
    }
  }
  __syncthreads();
#pragma unroll
  for (int i = 0; i < 2; ++i){
    int ch = i*256 + t; int n = ch>>3, c8 = (ch&7)*8;
    unsigned short tmp[8] __attribute__((aligned(16)));
#pragma unroll
    for (int j = 0; j < 8; ++j){
      int c = c8 + j;
      tmp[j] = tile[c][n ^ (((c>>3)&7)<<3)];
    }
    *(short8_t*)&xT[((size_t)(b*4096 + n0 + n))*512 + c0 + c8] = *(short8_t*)tmp;
  }
}

// ---------------- ql = w_q_lat @ latents (batch-independent), f32 ----------------
__global__ __launch_bounds__(256) void k_ql(const unsigned short* __restrict__ wqlat,
                                            const float* __restrict__ latf, float* __restrict__ ql){
  int o0 = blockIdx.x*64;
  extern __shared__ char smr[];
  float* latb = (float*)smr;                         // [128][16]
  unsigned short* wt = (unsigned short*)(smr + 8192); // [64][136]
  int t = threadIdx.x;
  int o = t>>2, l4 = (t&3)*4;
  float acc[4] = {0.f,0.f,0.f,0.f};
  for (int kk = 0; kk < 512; kk += 128){
    __syncthreads();
#pragma unroll
    for (int j = 0; j < 8; ++j){ int i = j*256 + t; latb[i] = latf[kk*16 + i]; }
#pragma unroll
    for (int j = 0; j < 4; ++j){ int ch = j*256 + t; int r = ch>>4, kc = (ch&15)*8;
      *(short8_t*)&wt[r*136 + kc] = *(const short8_t*)&wqlat[(size_t)(o0+r)*512 + kk + kc]; }
    __syncthreads();
    for (int k = 0; k < 128; ++k){
      float w = bf2f(wt[o*136 + k]);
      const float* lr = &latb[k*16 + l4];
#pragma unroll
      for (int j = 0; j < 4; ++j) acc[j] += w*lr[j];
    }
  }
#pragma unroll
  for (int j = 0; j < 4; ++j) ql[(o0+o)*16 + l4 + j] = acc[j];
}

// normalize ql over d per (h,l) -> qlhat [h][d][l]
__global__ void k_qlnorm(const float* __restrict__ ql, float* __restrict__ qlh){
  int l = blockIdx.x, h = blockIdx.y, d = threadIdx.x;
  float v = ql[(h*64 + d)*16 + l];
  float ss = v*v;
  for (int off = 32; off; off >>= 1) ss += __shfl_xor(ss, off);
  qlh[(h*64 + d)*16 + l] = v / fmaxf(sqrtf(ss), 1e-12f);
}

// ---------------- shared MFMA GEMM core: 64x128 tile, K=512, 4 waves (2x2) ----------------
// A: row-major [m][k] (k contiguous). B: row-major [n][k] (k contiguous), i.e. transposed source.
// D[m][n] = sum_k A[m][k]*B[n][k].  Verified layouts (guide §3):
//   A-frag: m=lane&15, k=(lane>>4)*8+j ; B-frag: n=lane&15, k=(lane>>4)*8+j
//   C/D  : col=lane&15, row=(lane>>4)*4+reg
DEV void gemm_core(const unsigned short* __restrict__ Ap, const unsigned short* __restrict__ Bp,
                   unsigned short* At, unsigned short* Bt, floatx4 (&acc)[2][4]){
  int t = threadIdx.x, lane = t&63, wave = t>>6;
  int wm = wave>>1, wn = wave&1, lr = lane&15, lq = lane>>4;
  for (int kk = 0; kk < 512; kk += 64){
    __syncthreads();
#pragma unroll
    for (int i = 0; i < 2; ++i){ int ch = i*256 + t; int r = ch>>3, kc = (ch&7)*8;
      *(short8_t*)&At[r*72 + kc] = *(const short8_t*)&Ap[(size_t)r*512 + kk + kc]; }
#pragma unroll
    for (int i = 0; i < 4; ++i){ int ch = i*256 + t; int r = ch>>3, kc = (ch&7)*8;
      *(short8_t*)&Bt[r*72 + kc] = *(const short8_t*)&Bp[(size_t)r*512 + kk + kc]; }
    __syncthreads();
#pragma unroll
    for (int ks = 0; ks < 2; ++ks){
      bf16x8 a0 = *(const bf16x8*)&At[(wm*32 + lr)*72 + ks*32 + lq*8];
      bf16x8 a1 = *(const bf16x8*)&At[(wm*32 + 16 + lr)*72 + ks*32 + lq*8];
#pragma unroll
      for (int nt = 0; nt < 4; ++nt){
        bf16x8 bb = *(const bf16x8*)&Bt[(wn*64 + nt*16 + lr)*72 + ks*32 + lq*8];
        acc[0][nt] = __builtin_amdgcn_mfma_f32_16x16x32_bf16(a0, bb, acc[0][nt], 0, 0, 0);
        acc[1][nt] = __builtin_amdgcn_mfma_f32_16x16x32_bf16(a1, bb, acc[1][nt], 0, 0, 0);
      }
    }
  }
  __syncthreads();  // protects LDS reuse by epilogues
}

// GEMM1: kvx[b][o][n] (bf16) = w_kv_x @ x
__global__ __launch_bounds__(256) void k_gemm_kvx(const unsigned short* __restrict__ wkvx,
                                                  const unsigned short* __restrict__ xT,
                                                  unsigned short* __restrict__ kvx){
  int nb = blockIdx.x, mb = blockIdx.y, b = blockIdx.z;
  int n0 = nb*128, o0 = mb*64;
  extern __shared__ char smr[];
  unsigned short* At = (unsigned short*)smr;
  unsigned short* Bt = At + 64*72;
  floatx4 acc[2][4];
  floatx4 zero = {0.f,0.f,0.f,0.f};
#pragma unroll
  for (int i = 0; i < 2; ++i) for (int j = 0; j < 4; ++j) acc[i][j] = zero;
  gemm_core(wkvx + (size_t)o0*512, xT + ((size_t)(b*4096 + n0))*512, At, Bt, acc);
  int t = threadIdx.x, lane = t&63, wave = t>>6;
  int wm = wave>>1, wn = wave&1, lr = lane&15, lq = lane>>4;
  unsigned short* ct = (unsigned short*)smr;  // [64][136]
#pragma unroll
  for (int mt = 0; mt < 2; ++mt)
#pragma unroll
    for (int nt = 0; nt < 4; ++nt)
#pragma unroll
      for (int r = 0; r < 4; ++r)
        ct[(wm*32 + mt*16 + lq*4 + r)*136 + wn*64 + nt*16 + lr] = f2bf(acc[mt][nt][r]);
  __syncthreads();
#pragma unroll
  for (int i = 0; i < 4; ++i){ int ch = i*256 + t; int r = ch>>4, c8 = (ch&15)*8;
    *(short8_t*)&kvx[((size_t)(b*1024 + o0 + r))*4096 + n0 + c8] = *(short8_t*)&ct[r*136 + c8]; }
}

// ---------------- attn1: split-K over positions, atomics for num/den ----------------
__global__ __launch_bounds__(256) void k_attn1(const unsigned short* __restrict__ kvx,
                                               const float* __restrict__ qlhat,
                                               float* __restrict__ gnum, float* __restrict__ gden){
  int nc = blockIdx.x, h = blockIdx.y, b = blockIdx.z;
  extern __shared__ char smr[];
  float* qlh  = (float*)smr;                                 // [64][16]
  float* pbuf = (float*)(smr + 4096);                        // [16][513]
  unsigned short* vbuf = (unsigned short*)(smr + 4096 + 32832); // [64][136]
  float* wred = (float*)(smr + 4096 + 32832 + 17408);        // [16][4]
  int t = threadIdx.x;
  for (int i = t; i < 1024; i += 256) qlh[i] = qlhat[h*1024 + i];
  __syncthreads();
  int n0 = nc*512;
  float dloc[16];
#pragma unroll
  for (int l = 0; l < 16; ++l) dloc[l] = 0.f;
  for (int pass = 0; pass < 2; ++pass){
    int nl = pass*256 + t;
    const unsigned short* kxp = kvx + ((size_t)(b*1024 + h*64))*4096 + n0 + nl;
    float dot[16];
#pragma unroll
    for (int l = 0; l < 16; ++l) dot[l] = 0.f;
    float ss = 0.f;
    for (int d = 0; d < 64; ++d){
      float kv = bf2f(kxp[(size_t)d*4096]);
      ss += kv*kv;
      const float* qr = &qlh[d*16];
#pragma unroll
      for (int l = 0; l < 16; ++l) dot[l] += kv*qr[l];
    }
    float inv = 0.125f / fmaxf(sqrtf(ss), 1e-12f);
#pragma unroll
    for (int l = 0; l < 16; ++l){ float p = __expf(dot[l]*inv); pbuf[l*513 + nl] = p; dloc[l] += p; }
  }
  int lane = t&63, wv = t>>6;
#pragma unroll
  for (int l = 0; l < 16; ++l){
    float s = dloc[l];
    for (int off = 32; off; off >>= 1) s += __shfl_xor(s, off);
    if (lane == 0) wred[l*4 + wv] = s;
  }
  __syncthreads();
  if (t < 16) atomicAdd(&gden[(b*8+h)*16 + t], wred[t*4]+wred[t*4+1]+wred[t*4+2]+wred[t*4+3]);
  int d = t>>2, l4 = (t&3)*4;
  float acc[4] = {0.f,0.f,0.f,0.f};
  for (int c = 0; c < 4; ++c){
    __syncthreads();
#pragma unroll
    for (int i = 0; i < 4; ++i){ int ch = i*256 + t; int r = ch>>4, n8 = (ch&15)*8;
      *(short8_t*)&vbuf[r*136 + n8] =
        *(const short8_t*)&kvx[((size_t)(b*1024 + 512 + h*64 + r))*4096 + n0 + c*128 + n8]; }
    __syncthreads();
    for (int n = 0; n < 128; ++n){
      float v = bf2f(vbuf[d*136 + n]);
      const float* pr = &pbuf[l4*513 + c*128 + n];
      acc[0] += v*pr[0];
      acc[1] += v*pr[513];
      acc[2] += v*pr[1026];
      acc[3] += v*pr[1539];
    }
  }
#pragma unroll
  for (int j = 0; j < 4; ++j) atomicAdd(&gnum[((size_t)((b*8+h)*16 + l4 + j))*64 + d], acc[j]);
}

// ---------------- kvl = w_kv_lat @ (num/den), f32 [b][o][l] ----------------
__global__ __launch_bounds__(256) void k_kvl(const unsigned short* __restrict__ wkvl,
                                             const float* __restrict__ gnum, const float* __restrict__ gden,
                                             float* __restrict__ kvl){
  int ob = blockIdx.x, b = blockIdx.y;
  extern __shared__ char smr[];
  float* latb = (float*)smr;                         // [512][16]
  unsigned short* wt = (unsigned short*)(smr + 32768); // [16][136]
  int t = threadIdx.x;
  for (int i = t; i < 8192; i += 256){
    int c = i>>4, l = i&15;
    int h = c>>6, d = c&63;
    int bh = b*8 + h;
    latb[i] = gnum[((size_t)(bh*16 + l))*64 + d] / gden[bh*16 + l];
  }
  int o = t>>4, l = t&15;
  int o0 = ob*16;
  float acc = 0.f;
  for (int kk = 0; kk < 512; kk += 128){
    __syncthreads();
    { int r = t>>4, kc = (t&15)*8;
      *(short8_t*)&wt[r*136 + kc] = *(const short8_t*)&wkvl[(size_t)(o0+r)*512 + kk + kc]; }
    __syncthreads();
    for (int k = 0; k < 128; ++k) acc += bf2f(wt[o*136 + k]) * latb[(kk+k)*16 + l];
  }
  kvl[((size_t)(b*1024 + o0 + o))*16 + l] = acc;
}

// normalize kl per (b,h,l), emit khat/vl as [b][h][l][d] f32
__global__ void k_klnorm(const float* __restrict__ kvl, float* __restrict__ khat, float* __restrict__ gvl){
  int l = blockIdx.x, h = blockIdx.y, b = blockIdx.z, d = threadIdx.x;
  float kl = kvl[((size_t)(b*1024 + h*64 + d))*16 + l];
  float vl = kvl[((size_t)(b*1024 + 512 + h*64 + d))*16 + l];
  float ss = kl*kl;
  for (int off = 32; off; off >>= 1) ss += __shfl_xor(ss, off);
  float inv = 1.f / fmaxf(sqrtf(ss), 1e-12f);
  size_t o = ((size_t)((b*8+h)*16 + l))*64 + d;
  khat[o] = kl*inv;
  gvl[o] = vl;
}

// ---------------- GEMM2 (qx) fused with attn2 -> xw[b][n][c] bf16 ----------------
__global__ __launch_bounds__(256) void k_attn2(const unsigned short* __restrict__ wqx,
                                               const unsigned short* __restrict__ xT,
                                               const float* __restrict__ khatg, const float* __restrict__ vlg,
                                               unsigned short* __restrict__ xw){
  int nb = blockIdx.x, h = blockIdx.y, b = blockIdx.z;
  int n0 = nb*128;
  extern __shared__ char smr[];
  unsigned short* At = (unsigned short*)smr;            // stage region 27648 B (reused: qt, then xwt)
  unsigned short* Bt = At + 64*72;
  float* sbuf  = (float*)(smr + 27648);                 // [16][129]
  float* khs   = (float*)(smr + 27648 + 8256);          // [16][64]
  float* vls   = (float*)(smr + 27648 + 8256 + 4096);   // [16][64]
  float* rnorm = (float*)(smr + 27648 + 8256 + 8192);   // [128]
  float* rsum  = rnorm + 128;                           // [128]
  int t = threadIdx.x;
  for (int i = t; i < 1024; i += 256){
    khs[i] = khatg[(size_t)(b*8+h)*1024 + i];
    vls[i] = vlg[(size_t)(b*8+h)*1024 + i];
  }
  floatx4 acc[2][4];
  floatx4 zero = {0.f,0.f,0.f,0.f};
#pragma unroll
  for (int i = 0; i < 2; ++i) for (int j = 0; j < 4; ++j) acc[i][j] = zero;
  gemm_core(wqx + (size_t)(h*64)*512, xT + ((size_t)(b*4096 + n0))*512, At, Bt, acc);
  int lane = t&63, wave = t>>6, wm = wave>>1, wn = wave&1, lr = lane&15, lq = lane>>4;
  unsigned short* qt = (unsigned short*)smr;  // [64][136] bf16 q-tile (d x n)
#pragma unroll
  for (int mt = 0; mt < 2; ++mt)
#pragma unroll
    for (int nt = 0; nt < 4; ++nt)
#pragma unroll
      for (int r = 0; r < 4; ++r)
        qt[(wm*32 + mt*16 + lq*4 + r)*136 + wn*64 + nt*16 + lr] = f2bf(acc[mt][nt][r]);
  __syncthreads();
  if (t < 128){
    float ss = 0.f;
    for (int d = 0; d < 64; ++d){ float q = bf2f(qt[d*136 + t]); ss += q*q; }
    rnorm[t] = 1.f / fmaxf(sqrtf(ss), 1e-12f);
  }
  __syncthreads();
  {
    int n = t&127, l8 = (t>>7)*8;
    float dot[8];
#pragma unroll
    for (int j = 0; j < 8; ++j) dot[j] = 0.f;
    for (int d0 = 0; d0 < 64; d0 += 4){
      float q0 = bf2f(qt[(d0+0)*136 + n]);
      float q1 = bf2f(qt[(d0+1)*136 + n]);
      float q2 = bf2f(qt[(d0+2)*136 + n]);
      float q3 = bf2f(qt[(d0+3)*136 + n]);
#pragma unroll
      for (int j = 0; j < 8; ++j){
        const float* kr = &khs[(l8+j)*64 + d0];
        dot[j] += q0*kr[0] + q1*kr[1] + q2*kr[2] + q3*kr[3];
      }
    }
    float sc = 0.125f * rnorm[n];
#pragma unroll
    for (int j = 0; j < 8; ++j) sbuf[(l8+j)*129 + n] = __expf(dot[j]*sc);
  }
  __syncthreads();
  if (t < 128){
    float s = 0.f;
#pragma unroll
    for (int l = 0; l < 16; ++l) s += sbuf[l*129 + t];
    rsum[t] = 1.f/s;
  }
  __syncthreads();
  float av[32];
#pragma unroll
  for (int i = 0; i < 32; ++i) av[i] = 0.f;
  int n2 = t&127, dh = t>>7;
  for (int l = 0; l < 16; ++l){
    float e = sbuf[l*129 + n2];
    const float* vr = &vls[l*64 + dh*32];
#pragma unroll
    for (int i = 0; i < 32; ++i) av[i] += e*vr[i];
  }
  float rs = rsum[n2];
  unsigned short* xwt = (unsigned short*)smr;   // [128][72]; qt dead (sync'd after last read)
#pragma unroll
  for (int i4 = 0; i4 < 4; ++i4){
    unsigned short tmp[8] __attribute__((aligned(16)));
#pragma unroll
    for (int j = 0; j < 8; ++j) tmp[j] = f2bf(av[i4*8 + j]*rs);
    *(short8_t*)&xwt[n2*72 + dh*32 + i4*8] = *(short8_t*)tmp;
  }
  __syncthreads();
#pragma unroll
  for (int i = 0; i < 4; ++i){ int ch = i*256 + t; int r = ch>>3, c8 = (ch&7)*8;
    *(short8_t*)&xw[((size_t)(b*4096 + n0 + r))*512 + h*64 + c8] = *(short8_t*)&xwt[r*72 + c8]; }
}

// ---------------- GEMM3: out = w_proj @ x_write + bias ----------------
__global__ __launch_bounds__(256) void k_gemm_out(const unsigned short* __restrict__ wproj,
                                                  const unsigned short* __restrict__ xw,
                                                  const float* __restrict__ biasf,
                                                  void* __restrict__ outv, const int* __restrict__ flag){
  int nb = blockIdx.x, mb = blockIdx.y, b = blockIdx.z;
  int n0 = nb*128, o0 = mb*64;
  extern __shared__ char smr[];
  unsigned short* At = (unsigned short*)smr;
  unsigned short* Bt = At + 64*72;
  floatx4 acc[2][4];
  floatx4 zero = {0.f,0.f,0.f,0.f};
#pragma unroll
  for (int i = 0; i < 2; ++i) for (int j = 0; j < 4; ++j) acc[i][j] = zero;
  gemm_core(wproj + (size_t)o0*512, xw + ((size_t)(b*4096 + n0))*512, At, Bt, acc);
  int t = threadIdx.x, lane = t&63, wave = t>>6;
  int wm = wave>>1, wn = wave&1, lr = lane&15, lq = lane>>4;
  unsigned short* ct = (unsigned short*)smr;  // [64][136]
#pragma unroll
  for (int mt = 0; mt < 2; ++mt)
#pragma unroll
    for (int nt = 0; nt < 4; ++nt)
#pragma unroll
      for (int r = 0; r < 4; ++r){
        int row = wm*32 + mt*16 + lq*4 + r;
        ct[row*136 + wn*64 + nt*16 + lr] = f2bf(acc[mt][nt][r] + biasf[o0 + row]);
      }
  __syncthreads();
  if (*flag){
    float* of = (float*)outv;
#pragma unroll
    for (int i = 0; i < 4; ++i){ int ch = i*256 + t; int r = ch>>4, c8 = (ch&15)*8;
      float tmp[8] __attribute__((aligned(16)));
#pragma unroll
      for (int j = 0; j < 8; ++j) tmp[j] = bf2f(ct[r*136 + c8 + j]);
      float4* dst = (float4*)&of[((size_t)(b*512 + o0 + r))*4096 + n0 + c8];
      dst[0] = *(float4*)&tmp[0];
      dst[1] = *(float4*)&tmp[4];
    }
  } else {
    unsigned short* ob = (unsigned short*)outv;
#pragma unroll
    for (int i = 0; i < 4; ++i){ int ch = i*256 + t; int r = ch>>4, c8 = (ch&15)*8;
      *(short8_t*)&ob[((size_t)(b*512 + o0 + r))*4096 + n0 + c8] = *(short8_t*)&ct[r*136 + c8]; }
  }
}

extern "C" void kernel_launch(void* const* d_in, const int* in_sizes, int n_in,
                              void* d_out, int out_size, void* d_ws, size_t ws_size,
                              hipStream_t stream){
  (void)in_sizes; (void)n_in; (void)out_size; (void)ws_size;
  char* ws = (char*)d_ws;
  int* flag              = (int*)ws;
  unsigned short* xT     = (unsigned short*)(ws + OFF_XT);
  unsigned short* kvx    = (unsigned short*)(ws + OFF_KVX);
  unsigned short* xw     = (unsigned short*)(ws + OFF_KVX);  // reuse (kvx dead after attn1)
  unsigned short* wkvx   = (unsigned short*)(ws + OFF_WKVX);
  unsigned short* wqx    = (unsigned short*)(ws + OFF_WQX);
  unsigned short* wkvl   = (unsigned short*)(ws + OFF_WKVL);
  unsigned short* wproj  = (unsigned short*)(ws + OFF_WPROJ);
  unsigned short* wqlat  = (unsigned short*)(ws + OFF_WQLAT);
  float* latf  = (float*)(ws + OFF_LATF);
  float* biasf = (float*)(ws + OFF_BIAS);
  float* ql    = (float*)(ws + OFF_QL);
  float* qlh   = (float*)(ws + OFF_QLH);
  float* gnum  = (float*)(ws + OFF_GNUM);
  float* gden  = (float*)(ws + OFF_GDEN);
  float* kvl   = (float*)(ws + OFF_KVL);
  float* khat  = (float*)(ws + OFF_KHAT);
  float* gvl   = (float*)(ws + OFF_GVL);

  k_sniff<<<1, 256, 0, stream>>>((const unsigned short*)d_in[0], flag);

  k_cvt<<<256, 256, 0, stream>>>(d_in[3], wkvx, 524288, flag);   // w_kv_x
  k_cvt<<<128, 256, 0, stream>>>(d_in[4], wqx,  262144, flag);   // w_q_x
  k_cvt<<<256, 256, 0, stream>>>(d_in[5], wkvl, 524288, flag);   // w_kv_lat
  k_cvt<<<128, 256, 0, stream>>>(d_in[6], wproj,262144, flag);   // w_proj
  k_cvt<<<128, 256, 0, stream>>>(d_in[2], wqlat,262144, flag);   // w_q_lat
  k_cvtf<<<32, 256, 0, stream>>>(d_in[1], latf, 8192, flag);     // latents
  k_cvtf<<<2, 256, 0, stream>>>(d_in[7], biasf, 512, flag);      // b_proj

  k_xt<<<dim3(64, 8, 8), 256, 0, stream>>>(d_in[0], xT, flag);

  k_ql<<<8, 256, 8192 + 64*136*2, stream>>>(wqlat, latf, ql);
  k_qlnorm<<<dim3(16, 8), 64, 0, stream>>>(ql, qlh);

  hipMemsetAsync(ws + OFF_GNUM, 0, 524288 + 4096, stream);       // gnum + gden

  k_gemm_kvx<<<dim3(32, 16, 8), 256, 27648, stream>>>(wkvx, xT, kvx);
  k_attn1<<<dim3(8, 8, 8), 256, 4096 + 32832 + 17408 + 256, stream>>>(kvx, qlh, gnum, gden);
  k_kvl<<<dim3(64, 8), 256, 32768 + 16*136*2, stream>>>(wkvl, gnum, gden, kvl);
  k_klnorm<<<dim3(16, 8, 8), 64, 0, stream>>>(kvl, khat, gvl);
  k_attn2<<<dim3(32, 8, 8), 256, 45120, stream>>>(wqx, xT, khat, gvl, xw);
  k_gemm_out<<<dim3(32, 8, 8), 256, 27648, stream>>>(wproj, xw, biasf, d_out, flag);
}

// Round 2
// 356.508 us; speedup vs baseline: 1.1435x; 1.1435x over previous
//
#include <hip/hip_runtime.h>

// LatentMixer on MI355X. bf16-MFMA pipeline with runtime input-dtype sniffing.
// B=8, C=512, HW=4096, L=16, heads=8, d=64, scale=0.125, eps=1e-12.
// R2: replaced attn2+gemm_out with algebraic fusion: out = (w_proj@blockdiag(V)) @ P + bias.

typedef __bf16 bf16x8 __attribute__((ext_vector_type(8)));
typedef float floatx4 __attribute__((ext_vector_type(4)));
typedef short short8_t __attribute__((ext_vector_type(8)));
typedef short short4_t __attribute__((ext_vector_type(4)));

#define DEV __device__ __forceinline__

DEV float bf2f(unsigned short u){ union{unsigned int i; float f;} v; v.i = ((unsigned int)u)<<16; return v.f; }
DEV unsigned short f2bf(float f){
  union{float f; unsigned int i;} v; v.f = f;
  unsigned int i = v.i;
  return (unsigned short)((i + 0x7fffu + ((i>>16)&1u)) >> 16);
}

// ---------------- workspace layout (bytes) ----------------
#define OFF_XT     256ull                          // xT bf16 [8][4096][512]
#define OFF_KVX    (OFF_XT + 33554432ull)          // kvx bf16 [8][1024][4096]; later reused: Pg + Mg
#define OFF_WKVX   (OFF_KVX + 67108864ull)         // w_kv_x bf16
#define OFF_WQX    (OFF_WKVX + 1048576ull)         // w_q_x bf16
#define OFF_WKVL   (OFF_WQX + 524288ull)           // w_kv_lat bf16
#define OFF_WPROJ  (OFF_WKVL + 1048576ull)         // w_proj bf16
#define OFF_WQLAT  (OFF_WPROJ + 524288ull)         // w_q_lat bf16
#define OFF_LATF   (OFF_WQLAT + 524288ull)         // latents f32 [512][16]
#define OFF_BIAS   (OFF_LATF + 32768ull)           // bias f32 [512]
#define OFF_QL     (OFF_BIAS + 4096ull)            // ql f32 [512][16]
#define OFF_QLH    (OFF_QL + 32768ull)             // ql-hat f32 [8][64][16]
#define OFF_GNUM   (OFF_QLH + 32768ull)            // attn1 numerator f32 [b][h][l][64]
#define OFF_GDEN   (OFF_GNUM + 524288ull)          // attn1 denominator f32 [b][h][l]
#define OFF_KVL    (OFF_GDEN + 4096ull)            // kvl f32 [b][1024][16]
#define OFF_KHAT   (OFF_KVL + 524288ull)           // k-hat f32 [b][h][l][64]
#define OFF_GVL    (OFF_KHAT + 524288ull)          // vl f32 [b][h][l][64]

// ---------------- dtype sniff ----------------
__global__ void k_sniff(const unsigned short* __restrict__ x, int* flag){
  int t = threadIdx.x;
  int m = 0;
  for (int i = t; i < 4096; i += 256){ int e = (x[i]>>7)&0xFF; m = (e>m)?e:m; }
  __shared__ int red[256];
  red[t] = m; __syncthreads();
  for (int s = 128; s > 0; s >>= 1){ if (t < s) red[t] = (red[t+s]>red[t])?red[t+s]:red[t]; __syncthreads(); }
  if (t == 0) flag[0] = (red[0] > 150) ? 1 : 0;   // 1 => fp32 inputs, 0 => bf16 inputs
}

// convert (or copy) a weight array to bf16
__global__ __launch_bounds__(256) void k_cvt(const void* __restrict__ src, unsigned short* __restrict__ dst,
                                             int n, const int* __restrict__ flag){
  int base = (blockIdx.x*256 + threadIdx.x)*8;
  if (base >= n) return;
  if (*flag){
    const float* s = (const float*)src + base;
    float4 v0 = *(const float4*)(s);
    float4 v1 = *(const float4*)(s+4);
    unsigned short tmp[8] __attribute__((aligned(16)));
    tmp[0]=f2bf(v0.x); tmp[1]=f2bf(v0.y); tmp[2]=f2bf(v0.z); tmp[3]=f2bf(v0.w);
    tmp[4]=f2bf(v1.x); tmp[5]=f2bf(v1.y); tmp[6]=f2bf(v1.z); tmp[7]=f2bf(v1.w);
    *(short8_t*)&dst[base] = *(short8_t*)tmp;
  } else {
    *(short8_t*)&dst[base] = *(const short8_t*)((const unsigned short*)src + base);
  }
}

// convert to f32 (latents, bias)
__global__ void k_cvtf(const void* __restrict__ src, float* __restrict__ dst, int n, const int* __restrict__ flag){
  int i = blockIdx.x*256 + threadIdx.x;
  if (i >= n) return;
  dst[i] = (*flag) ? ((const float*)src)[i] : bf2f(((const unsigned short*)src)[i]);
}

// ---------------- transpose x[b][c][n] -> xT[b][n][c] (bf16) ----------------
__global__ __launch_bounds__(256) void k_xt(const void* __restrict__ xraw, unsigned short* __restrict__ xT,
                                            const int* __restrict__ flag){
  int nb = blockIdx.x, cb = blockIdx.y, b = blockIdx.z;
  int n0 = nb*64, c0 = cb*64;
  __shared__ unsigned short tile[64][72];   // XOR-swizzled columns: col = n ^ (((row>>3)&7)<<3)
  int t = threadIdx.x;
  if (*flag){
    const float* xp = (const float*)xraw;
#pragma unroll
    for (int i = 0; i < 4; ++i){
      int ch = i*256 + t; int c = ch>>4, n4 = (ch&15)*4;
      float4 v = *(const float4*)&xp[((size_t)(b*512 + c0 + c))*4096 + n0 + n4];
      int cc = n4 ^ (((c>>3)&7)<<3);
      tile[c][cc+0]=f2bf(v.x); tile[c][cc+1]=f2bf(v.y); tile[c][cc+2]=f2bf(v.z); tile[c][cc+3]=f2bf(v.w);
    }
  } else {
    const unsigned short* xp = (const unsigned short*)xraw;
#pragma unroll
    for (int i = 0; i < 2; ++i){
      int ch = i*256 + t; int c = ch>>3, n8 = (ch&7)*8;
      *(short8_t*)&tile[c][n8 ^ (((c>>3)&7)<<3)] =
        *(const short8_t*)&xp[((size_t)(b*512 + c0 + c))*4096 + n0 + n8];
    }
  }
  __syncthreads();
#pragma unroll
  for (int i = 0; i < 2; ++i){
    int ch = i*256 + t; int n = ch>>3, c8 = (ch&7)*8;
    unsigned short tmp[8] __attribute__((aligned(16)));
#pragma unroll
    for (int j = 0; j < 8; ++j){
      int c = c8 + j;
      tmp[j] = tile[c][n ^ (((c>>3)&7)<<3)];
    }
    *(short8_t*)&xT[((size_t)(b*4096 + n0 + n))*512 + c0 + c8] = *(short8_t*)tmp;
  }
}

// ---------------- ql = w_q_lat @ latents (batch-independent), f32 ----------------
__global__ __launch_bounds__(256) void k_ql(const unsigned short* __restrict__ wqlat,
                                            const float* __restrict__ latf, float* __restrict__ ql){
  int o0 = blockIdx.x*64;
  extern __shared__ char smr[];
  float* latb = (float*)smr;                         // [128][16]
  unsigned short* wt = (unsigned short*)(smr + 8192); // [64][136]
  int t = threadIdx.x;
  int o = t>>2, l4 = (t&3)*4;
  float acc[4] = {0.f,0.f,0.f,0.f};
  for (int kk = 0; kk < 512; kk += 128){
    __syncthreads();
#pragma unroll
    for (int j = 0; j < 8; ++j){ int i = j*256 + t; latb[i] = latf[kk*16 + i]; }
#pragma unroll
    for (int j = 0; j < 4; ++j){ int ch = j*256 + t; int r = ch>>4, kc = (ch&15)*8;
      *(short8_t*)&wt[r*136 + kc] = *(const short8_t*)&wqlat[(size_t)(o0+r)*512 + kk + kc]; }
    __syncthreads();
    for (int k = 0; k < 128; ++k){
      float w = bf2f(wt[o*136 + k]);
      const float* lr = &latb[k*16 + l4];
#pragma unroll
      for (int j = 0; j < 4; ++j) acc[j] += w*lr[j];
    }
  }
#pragma unroll
  for (int j = 0; j < 4; ++j) ql[(o0+o)*16 + l4 + j] = acc[j];
}

// normalize ql over d per (h,l) -> qlhat [h][d][l]
__global__ void k_qlnorm(const float* __restrict__ ql, float* __restrict__ qlh){
  int l = blockIdx.x, h = blockIdx.y, d = threadIdx.x;
  float v = ql[(h*64 + d)*16 + l];
  float ss = v*v;
  for (int off = 32; off; off >>= 1) ss += __shfl_xor(ss, off);
  qlh[(h*64 + d)*16 + l] = v / fmaxf(sqrtf(ss), 1e-12f);
}

// ---------------- shared MFMA GEMM core: 64x128 tile, K=512, 4 waves (2x2) ----------------
DEV void gemm_core(const unsigned short* __restrict__ Ap, const unsigned short* __restrict__ Bp,
                   unsigned short* At, unsigned short* Bt, floatx4 (&acc)[2][4]){
  int t = threadIdx.x, lane = t&63, wave = t>>6;
  int wm = wave>>1, wn = wave&1, lr = lane&15, lq = lane>>4;
  for (int kk = 0; kk < 512; kk += 64){
    __syncthreads();
#pragma unroll
    for (int i = 0; i < 2; ++i){ int ch = i*256 + t; int r = ch>>3, kc = (ch&7)*8;
      *(short8_t*)&At[r*72 + kc] = *(const short8_t*)&Ap[(size_t)r*512 + kk + kc]; }
#pragma unroll
    for (int i = 0; i < 4; ++i){ int ch = i*256 + t; int r = ch>>3, kc = (ch&7)*8;
      *(short8_t*)&Bt[r*72 + kc] = *(const short8_t*)&Bp[(size_t)r*512 + kk + kc]; }
    __syncthreads();
#pragma unroll
    for (int ks = 0; ks < 2; ++ks){
      bf16x8 a0 = *(const bf16x8*)&At[(wm*32 + lr)*72 + ks*32 + lq*8];
      bf16x8 a1 = *(const bf16x8*)&At[(wm*32 + 16 + lr)*72 + ks*32 + lq*8];
#pragma unroll
      for (int nt = 0; nt < 4; ++nt){
        bf16x8 bb = *(const bf16x8*)&Bt[(wn*64 + nt*16 + lr)*72 + ks*32 + lq*8];
        acc[0][nt] = __builtin_amdgcn_mfma_f32_16x16x32_bf16(a0, bb, acc[0][nt], 0, 0, 0);
        acc[1][nt] = __builtin_amdgcn_mfma_f32_16x16x32_bf16(a1, bb, acc[1][nt], 0, 0, 0);
      }
    }
  }
  __syncthreads();  // protects LDS reuse by epilogues
}

// GEMM1: kvx[b][o][n] (bf16) = w_kv_x @ x
__global__ __launch_bounds__(256) void k_gemm_kvx(const unsigned short* __restrict__ wkvx,
                                                  const unsigned short* __restrict__ xT,
                                                  unsigned short* __restrict__ kvx){
  int nb = blockIdx.x, mb = blockIdx.y, b = blockIdx.z;
  int n0 = nb*128, o0 = mb*64;
  extern __shared__ char smr[];
  unsigned short* At = (unsigned short*)smr;
  unsigned short* Bt = At + 64*72;
  floatx4 acc[2][4];
  floatx4 zero = {0.f,0.f,0.f,0.f};
#pragma unroll
  for (int i = 0; i < 2; ++i) for (int j = 0; j < 4; ++j) acc[i][j] = zero;
  gemm_core(wkvx + (size_t)o0*512, xT + ((size_t)(b*4096 + n0))*512, At, Bt, acc);
  int t = threadIdx.x, lane = t&63, wave = t>>6;
  int wm = wave>>1, wn = wave&1, lr = lane&15, lq = lane>>4;
  unsigned short* ct = (unsigned short*)smr;  // [64][136]
#pragma unroll
  for (int mt = 0; mt < 2; ++mt)
#pragma unroll
    for (int nt = 0; nt < 4; ++nt)
#pragma unroll
      for (int r = 0; r < 4; ++r)
        ct[(wm*32 + mt*16 + lq*4 + r)*136 + wn*64 + nt*16 + lr] = f2bf(acc[mt][nt][r]);
  __syncthreads();
#pragma unroll
  for (int i = 0; i < 4; ++i){ int ch = i*256 + t; int r = ch>>4, c8 = (ch&15)*8;
    *(short8_t*)&kvx[((size_t)(b*1024 + o0 + r))*4096 + n0 + c8] = *(short8_t*)&ct[r*136 + c8]; }
}

// ---------------- attn1: split-K over positions, atomics for num/den ----------------
__global__ __launch_bounds__(256) void k_attn1(const unsigned short* __restrict__ kvx,
                                               const float* __restrict__ qlhat,
                                               float* __restrict__ gnum, float* __restrict__ gden){
  int nc = blockIdx.x, h = blockIdx.y, b = blockIdx.z;
  extern __shared__ char smr[];
  float* qlh  = (float*)smr;                                 // [64][16]
  float* pbuf = (float*)(smr + 4096);                        // [16][513]
  unsigned short* vbuf = (unsigned short*)(smr + 4096 + 32832); // [64][136]
  float* wred = (float*)(smr + 4096 + 32832 + 17408);        // [16][4]
  int t = threadIdx.x;
  for (int i = t; i < 1024; i += 256) qlh[i] = qlhat[h*1024 + i];
  __syncthreads();
  int n0 = nc*512;
  float dloc[16];
#pragma unroll
  for (int l = 0; l < 16; ++l) dloc[l] = 0.f;
  for (int pass = 0; pass < 2; ++pass){
    int nl = pass*256 + t;
    const unsigned short* kxp = kvx + ((size_t)(b*1024 + h*64))*4096 + n0 + nl;
    float dot[16];
#pragma unroll
    for (int l = 0; l < 16; ++l) dot[l] = 0.f;
    float ss = 0.f;
    for (int d = 0; d < 64; ++d){
      float kv = bf2f(kxp[(size_t)d*4096]);
      ss += kv*kv;
      const float* qr = &qlh[d*16];
#pragma unroll
      for (int l = 0; l < 16; ++l) dot[l] += kv*qr[l];
    }
    float inv = 0.125f / fmaxf(sqrtf(ss), 1e-12f);
#pragma unroll
    for (int l = 0; l < 16; ++l){ float p = __expf(dot[l]*inv); pbuf[l*513 + nl] = p; dloc[l] += p; }
  }
  int lane = t&63, wv = t>>6;
#pragma unroll
  for (int l = 0; l < 16; ++l){
    float s = dloc[l];
    for (int off = 32; off; off >>= 1) s += __shfl_xor(s, off);
    if (lane == 0) wred[l*4 + wv] = s;
  }
  __syncthreads();
  if (t < 16) atomicAdd(&gden[(b*8+h)*16 + t], wred[t*4]+wred[t*4+1]+wred[t*4+2]+wred[t*4+3]);
  int d = t>>2, l4 = (t&3)*4;
  float acc[4] = {0.f,0.f,0.f,0.f};
  for (int c = 0; c < 4; ++c){
    __syncthreads();
#pragma unroll
    for (int i = 0; i < 4; ++i){ int ch = i*256 + t; int r = ch>>4, n8 = (ch&15)*8;
      *(short8_t*)&vbuf[r*136 + n8] =
        *(const short8_t*)&kvx[((size_t)(b*1024 + 512 + h*64 + r))*4096 + n0 + c*128 + n8]; }
    __syncthreads();
    for (int n = 0; n < 128; ++n){
      float v = bf2f(vbuf[d*136 + n]);
      const float* pr = &pbuf[l4*513 + c*128 + n];
      acc[0] += v*pr[0];
      acc[1] += v*pr[513];
      acc[2] += v*pr[1026];
      acc[3] += v*pr[1539];
    }
  }
#pragma unroll
  for (int j = 0; j < 4; ++j) atomicAdd(&gnum[((size_t)((b*8+h)*16 + l4 + j))*64 + d], acc[j]);
}

// ---------------- kvl = w_kv_lat @ (num/den), f32 [b][o][l] ----------------
__global__ __launch_bounds__(256) void k_kvl(const unsigned short* __restrict__ wkvl,
                                             const float* __restrict__ gnum, const float* __restrict__ gden,
                                             float* __restrict__ kvl){
  int ob = blockIdx.x, b = blockIdx.y;
  extern __shared__ char smr[];
  float* latb = (float*)smr;                         // [512][16]
  unsigned short* wt = (unsigned short*)(smr + 32768); // [16][136]
  int t = threadIdx.x;
  for (int i = t; i < 8192; i += 256){
    int c = i>>4, l = i&15;
    int h = c>>6, d = c&63;
    int bh = b*8 + h;
    latb[i] = gnum[((size_t)(bh*16 + l))*64 + d] / gden[bh*16 + l];
  }
  int o = t>>4, l = t&15;
  int o0 = ob*16;
  float acc = 0.f;
  for (int kk = 0; kk < 512; kk += 128){
    __syncthreads();
    { int r = t>>4, kc = (t&15)*8;
      *(short8_t*)&wt[r*136 + kc] = *(const short8_t*)&wkvl[(size_t)(o0+r)*512 + kk + kc]; }
    __syncthreads();
    for (int k = 0; k < 128; ++k) acc += bf2f(wt[o*136 + k]) * latb[(kk+k)*16 + l];
  }
  kvl[((size_t)(b*1024 + o0 + o))*16 + l] = acc;
}

// normalize kl per (b,h,l), emit khat/vl as [b][h][l][d] f32
__global__ void k_klnorm(const float* __restrict__ kvl, float* __restrict__ khat, float* __restrict__ gvl){
  int l = blockIdx.x, h = blockIdx.y, b = blockIdx.z, d = threadIdx.x;
  float kl = kvl[((size_t)(b*1024 + h*64 + d))*16 + l];
  float vl = kvl[((size_t)(b*1024 + 512 + h*64 + d))*16 + l];
  float ss = kl*kl;
  for (int off = 32; off; off >>= 1) ss += __shfl_xor(ss, off);
  float inv = 1.f / fmaxf(sqrtf(ss), 1e-12f);
  size_t o = ((size_t)((b*8+h)*16 + l))*64 + d;
  khat[o] = kl*inv;
  gvl[o] = vl;
}

// ---------------- Mmat: M[b][c][h*16+l] = sum_d wproj[c][h*64+d] * vl[b][h][l][d] ----------------
__global__ __launch_bounds__(256) void k_mmat(const unsigned short* __restrict__ wproj,
                                              const float* __restrict__ gvl,
                                              unsigned short* __restrict__ Mg){
  int cb = blockIdx.x, h = blockIdx.y, b = blockIdx.z;
  __shared__ unsigned short wt[128*68];
  int t = threadIdx.x;
#pragma unroll
  for (int i = 0; i < 4; ++i){ int ch = i*256 + t; int c = ch>>3, d8 = (ch&7)*8;
    *(short8_t*)&wt[c*68 + d8] = *(const short8_t*)&wproj[(size_t)(cb*128 + c)*512 + h*64 + d8]; }
  int l = t&15, cq = t>>4;
  float v[64];
  const float* vp = &gvl[((size_t)(b*8+h)*16 + l)*64];
#pragma unroll
  for (int j = 0; j < 16; ++j){ float4 f = *(const float4*)&vp[j*4];
    v[j*4+0]=f.x; v[j*4+1]=f.y; v[j*4+2]=f.z; v[j*4+3]=f.w; }
  __syncthreads();
#pragma unroll
  for (int c8 = 0; c8 < 8; ++c8){
    int c = cq*8 + c8;
    float dot = 0.f;
#pragma unroll
    for (int d = 0; d < 64; ++d) dot += bf2f(wt[c*68 + d]) * v[d];
    Mg[((size_t)(b*512) + cb*128 + c)*128 + h*16 + l] = f2bf(dot);
  }
}

// ---------------- attn2 probabilities: q-GEMM + MFMA dots + softmax -> P[b][n][128] bf16 ----------------
__global__ __launch_bounds__(256) void k_attn2p(const unsigned short* __restrict__ wqx,
                                                const unsigned short* __restrict__ xT,
                                                const float* __restrict__ khatg,
                                                unsigned short* __restrict__ Pg){
  int nb = blockIdx.x, h = blockIdx.y, b = blockIdx.z;
  int n0 = nb*128;
  extern __shared__ char smr[];
  unsigned short* At = (unsigned short*)smr;
  unsigned short* Bt = At + 64*72;
  unsigned short* qt = (unsigned short*)smr;             // [128][72] (n x d), overlays At/Bt
  unsigned short* khs = (unsigned short*)(smr + 27648);  // [16][72] bf16 k-hat
  float* ssqp  = (float*)(smr + 29952);                  // [2][128]
  float* rnorm = (float*)(smr + 30976);                  // [128]  (0.125 / ||q_n||)
  int t = threadIdx.x, lane = t&63, wave = t>>6;
  int wm = wave>>1, wn = wave&1, lr = lane&15, lq = lane>>4;
  floatx4 acc[2][4];
  floatx4 zero = {0.f,0.f,0.f,0.f};
#pragma unroll
  for (int i = 0; i < 2; ++i) for (int j = 0; j < 4; ++j) acc[i][j] = zero;
  gemm_core(wqx + (size_t)(h*64)*512, xT + ((size_t)(b*4096 + n0))*512, At, Bt, acc);
  // write q-tile transposed: qt[n][d], d contiguous (A-operand layout for S-mfma)
#pragma unroll
  for (int mt = 0; mt < 2; ++mt)
#pragma unroll
    for (int nt = 0; nt < 4; ++nt){
      unsigned short tmp[4] __attribute__((aligned(8)));
#pragma unroll
      for (int r = 0; r < 4; ++r) tmp[r] = f2bf(acc[mt][nt][r]);
      *(short4_t*)&qt[(wn*64 + nt*16 + lr)*72 + wm*32 + mt*16 + lq*4] = *(short4_t*)tmp;
    }
  // per-column sum of squares (from f32 accumulators)
#pragma unroll
  for (int nt = 0; nt < 4; ++nt){
    float s = 0.f;
#pragma unroll
    for (int mt = 0; mt < 2; ++mt)
#pragma unroll
      for (int r = 0; r < 4; ++r) s += acc[mt][nt][r]*acc[mt][nt][r];
    s += __shfl_xor(s, 16); s += __shfl_xor(s, 32);
    if (lq == 0) ssqp[wm*128 + wn*64 + nt*16 + lr] = s;
  }
  // stage k-hat bf16 [16][72]
  for (int i = t; i < 1024; i += 256)
    khs[(i>>6)*72 + (i&63)] = f2bf(khatg[(size_t)(b*8+h)*1024 + i]);
  __syncthreads();
  if (t < 128) rnorm[t] = 0.125f / fmaxf(sqrtf(ssqp[t] + ssqp[128 + t]), 1e-12f);
  __syncthreads();
  // S[n][l] via MFMA: each wave does 2 m-tiles of 16 n; K=64 (2 steps)
  floatx4 sl[2];
  sl[0] = zero; sl[1] = zero;
#pragma unroll
  for (int ks = 0; ks < 2; ++ks){
    bf16x8 bb = *(const bf16x8*)&khs[lr*72 + ks*32 + lq*8];
#pragma unroll
    for (int i = 0; i < 2; ++i){
      bf16x8 aa = *(const bf16x8*)&qt[((wave*2 + i)*16 + lr)*72 + ks*32 + lq*8];
      sl[i] = __builtin_amdgcn_mfma_f32_16x16x32_bf16(aa, bb, sl[i], 0, 0, 0);
    }
  }
  // softmax over l (lanes lr hold l), write normalized probs (bf16)
#pragma unroll
  for (int i = 0; i < 2; ++i){
    int nb4 = (wave*2 + i)*16 + lq*4;
    float p[4], s[4];
#pragma unroll
    for (int r = 0; r < 4; ++r){ p[r] = __expf(sl[i][r] * rnorm[nb4 + r]); s[r] = p[r]; }
#pragma unroll
    for (int r = 0; r < 4; ++r){
      s[r] += __shfl_xor(s[r], 1);
      s[r] += __shfl_xor(s[r], 2);
      s[r] += __shfl_xor(s[r], 4);
      s[r] += __shfl_xor(s[r], 8);
    }
#pragma unroll
    for (int r = 0; r < 4; ++r)
      Pg[((size_t)(b*4096 + n0 + nb4 + r))*128 + h*16 + lr] = f2bf(p[r]/s[r]);
  }
}

// ---------------- out = M @ P + bias: 64x128 tile, K=128 ----------------
__global__ __launch_bounds__(256) void k_out(const unsigned short* __restrict__ Mg,
                                             const unsigned short* __restrict__ Pg,
                                             const float* __restrict__ biasf,
                                             void* __restrict__ outv, const int* __restrict__ flag){
  int nb = blockIdx.x, cb = blockIdx.y, b = blockIdx.z;
  int n0 = nb*128, c0 = cb*64;
  extern __shared__ char smr[];
  unsigned short* At = (unsigned short*)smr;   // [64][136]
  unsigned short* Bt = At + 64*136;            // [128][136]
  int t = threadIdx.x, lane = t&63, wave = t>>6;
  int wm = wave>>1, wn = wave&1, lr = lane&15, lq = lane>>4;
#pragma unroll
  for (int i = 0; i < 4; ++i){ int ch = i*256 + t; int r = ch>>4, p8 = (ch&15)*8;
    *(short8_t*)&At[r*136 + p8] = *(const short8_t*)&Mg[((size_t)(b*512 + c0 + r))*128 + p8]; }
#pragma unroll
  for (int i = 0; i < 8; ++i){ int ch = i*256 + t; int r = ch>>4, p8 = (ch&15)*8;
    *(short8_t*)&Bt[r*136 + p8] = *(const short8_t*)&Pg[((size_t)(b*4096 + n0 + r))*128 + p8]; }
  __syncthreads();
  floatx4 acc[2][4];
  floatx4 zero = {0.f,0.f,0.f,0.f};
#pragma unroll
  for (int i = 0; i < 2; ++i) for (int j = 0; j < 4; ++j) acc[i][j] = zero;
#pragma unroll
  for (int ks = 0; ks < 4; ++ks){
    bf16x8 a0 = *(const bf16x8*)&At[(wm*32 + lr)*136 + ks*32 + lq*8];
    bf16x8 a1 = *(const bf16x8*)&At[(wm*32 + 16 + lr)*136 + ks*32 + lq*8];
#pragma unroll
    for (int nt = 0; nt < 4; ++nt){
      bf16x8 bb = *(const bf16x8*)&Bt[(wn*64 + nt*16 + lr)*136 + ks*32 + lq*8];
      acc[0][nt] = __builtin_amdgcn_mfma_f32_16x16x32_bf16(a0, bb, acc[0][nt], 0, 0, 0);
      acc[1][nt] = __builtin_amdgcn_mfma_f32_16x16x32_bf16(a1, bb, acc[1][nt], 0, 0, 0);
    }
  }
  __syncthreads();
  float* ct = (float*)smr;  // [64][132] f32
#pragma unroll
  for (int mt = 0; mt < 2; ++mt)
#pragma unroll
    for (int nt = 0; nt < 4; ++nt)
#pragma unroll
      for (int r = 0; r < 4; ++r){
        int row = wm*32 + mt*16 + lq*4 + r;
        ct[row*132 + wn*64 + nt*16 + lr] = acc[mt][nt][r] + biasf[c0 + row];
      }
  __syncthreads();
  if (*flag){
    float* of = (float*)outv;
#pragma unroll
    for (int i = 0; i < 8; ++i){ int ch = i*256 + t; int r = ch>>5, c4 = (ch&31)*4;
      *(float4*)&of[((size_t)(b*512 + c0 + r))*4096 + n0 + c4] = *(float4*)&ct[r*132 + c4]; }
  } else {
    unsigned short* ob = (unsigned short*)outv;
#pragma unroll
    for (int i = 0; i < 4; ++i){ int ch = i*256 + t; int r = ch>>4, c8 = (ch&15)*8;
      unsigned short tmp[8] __attribute__((aligned(16)));
#pragma unroll
      for (int j = 0; j < 8; ++j) tmp[j] = f2bf(ct[r*132 + c8 + j]);
      *(short8_t*)&ob[((size_t)(b*512 + c0 + r))*4096 + n0 + c8] = *(short8_t*)tmp; }
  }
}

extern "C" void kernel_launch(void* const* d_in, const int* in_sizes, int n_in,
                              void* d_out, int out_size, void* d_ws, size_t ws_size,
                              hipStream_t stream){
  (void)in_sizes; (void)n_in; (void)out_size; (void)ws_size;
  char* ws = (char*)d_ws;
  int* flag              = (int*)ws;
  unsigned short* xT     = (unsigned short*)(ws + OFF_XT);
  unsigned short* kvx    = (unsigned short*)(ws + OFF_KVX);
  unsigned short* Pg     = (unsigned short*)(ws + OFF_KVX);              // overlays kvx (dead after attn1)
  unsigned short* Mg     = (unsigned short*)(ws + OFF_KVX + 8388608ull); // after Pg
  unsigned short* wkvx   = (unsigned short*)(ws + OFF_WKVX);
  unsigned short* wqx    = (unsigned short*)(ws + OFF_WQX);
  unsigned short* wkvl   = (unsigned short*)(ws + OFF_WKVL);
  unsigned short* wproj  = (unsigned short*)(ws + OFF_WPROJ);
  unsigned short* wqlat  = (unsigned short*)(ws + OFF_WQLAT);
  float* latf  = (float*)(ws + OFF_LATF);
  float* biasf = (float*)(ws + OFF_BIAS);
  float* ql    = (float*)(ws + OFF_QL);
  float* qlh   = (float*)(ws + OFF_QLH);
  float* gnum  = (float*)(ws + OFF_GNUM);
  float* gden  = (float*)(ws + OFF_GDEN);
  float* kvl   = (float*)(ws + OFF_KVL);
  float* khat  = (float*)(ws + OFF_KHAT);
  float* gvl   = (float*)(ws + OFF_GVL);

  k_sniff<<<1, 256, 0, stream>>>((const unsigned short*)d_in[0], flag);

  k_cvt<<<256, 256, 0, stream>>>(d_in[3], wkvx, 524288, flag);   // w_kv_x
  k_cvt<<<128, 256, 0, stream>>>(d_in[4], wqx,  262144, flag);   // w_q_x
  k_cvt<<<256, 256, 0, stream>>>(d_in[5], wkvl, 524288, flag);   // w_kv_lat
  k_cvt<<<128, 256, 0, stream>>>(d_in[6], wproj,262144, flag);   // w_proj
  k_cvt<<<128, 256, 0, stream>>>(d_in[2], wqlat,262144, flag);   // w_q_lat
  k_cvtf<<<32, 256, 0, stream>>>(d_in[1], latf, 8192, flag);     // latents
  k_cvtf<<<2, 256, 0, stream>>>(d_in[7], biasf, 512, flag);      // b_proj

  k_xt<<<dim3(64, 8, 8), 256, 0, stream>>>(d_in[0], xT, flag);

  k_ql<<<8, 256, 8192 + 64*136*2, stream>>>(wqlat, latf, ql);
  k_qlnorm<<<dim3(16, 8), 64, 0, stream>>>(ql, qlh);

  hipMemsetAsync(ws + OFF_GNUM, 0, 524288 + 4096, stream);       // gnum + gden

  k_gemm_kvx<<<dim3(32, 16, 8), 256, 27648, stream>>>(wkvx, xT, kvx);
  k_attn1<<<dim3(8, 8, 8), 256, 4096 + 32832 + 17408 + 256, stream>>>(kvx, qlh, gnum, gden);
  k_kvl<<<dim3(64, 8), 256, 32768 + 16*136*2, stream>>>(wkvl, gnum, gden, kvl);
  k_klnorm<<<dim3(16, 8, 8), 64, 0, stream>>>(kvl, khat, gvl);
  k_mmat<<<dim3(4, 8, 8), 256, 0, stream>>>(wproj, gvl, Mg);
  k_attn2p<<<dim3(32, 8, 8), 256, 31488, stream>>>(wqx, xT, khat, Pg);
  k_out<<<dim3(32, 8, 8), 256, 52224, stream>>>(Mg, Pg, biasf, d_out, flag);
}

// Round 3
// 314.785 us; speedup vs baseline: 1.2951x; 1.1325x over previous
//
#include <hip/hip_runtime.h>

// LatentMixer on MI355X. bf16-MFMA pipeline with runtime input-dtype sniffing.
// B=8, C=512, HW=4096, L=16, heads=8, d=64, scale=0.125, eps=1e-12.
// R2: out = (w_proj@blockdiag(V)) @ P + bias (algebraic fusion).
// R3: attn1 fused into kv-GEMM epilogue (no kvx materialization); 128x128 tiles.

typedef __bf16 bf16x8 __attribute__((ext_vector_type(8)));
typedef float floatx4 __attribute__((ext_vector_type(4)));
typedef short short8_t __attribute__((ext_vector_type(8)));
typedef short short4_t __attribute__((ext_vector_type(4)));

#define DEV __device__ __forceinline__

DEV float bf2f(unsigned short u){ union{unsigned int i; float f;} v; v.i = ((unsigned int)u)<<16; return v.f; }
DEV unsigned short f2bf(float f){
  union{float f; unsigned int i;} v; v.f = f;
  unsigned int i = v.i;
  return (unsigned short)((i + 0x7fffu + ((i>>16)&1u)) >> 16);
}

// ---------------- workspace layout (bytes) ----------------
#define OFF_XT     256ull                          // xT bf16 [8][4096][512]
#define OFF_KVX    (OFF_XT + 33554432ull)          // region reused: Pg bf16 [8][4096][128] + Mg
#define OFF_WKVX   (OFF_KVX + 67108864ull)         // w_kv_x bf16
#define OFF_WQX    (OFF_WKVX + 1048576ull)         // w_q_x bf16
#define OFF_WKVL   (OFF_WQX + 524288ull)           // w_kv_lat bf16
#define OFF_WPROJ  (OFF_WKVL + 1048576ull)         // w_proj bf16
#define OFF_WQLAT  (OFF_WPROJ + 524288ull)         // w_q_lat bf16
#define OFF_LATF   (OFF_WQLAT + 524288ull)         // latents f32 [512][16]
#define OFF_BIAS   (OFF_LATF + 32768ull)           // bias f32 [512]
#define OFF_QL     (OFF_BIAS + 4096ull)            // ql f32 [512][16]
#define OFF_QLH    (OFF_QL + 32768ull)             // ql-hat f32 [h][l][64] (0.125 folded)
#define OFF_GNUM   (OFF_QLH + 32768ull)            // attn1 numerator f32 [b][h][l][64]
#define OFF_GDEN   (OFF_GNUM + 524288ull)          // attn1 denominator f32 [b][h][l]
#define OFF_KVL    (OFF_GDEN + 4096ull)            // kvl f32 [b][1024][16]
#define OFF_KHAT   (OFF_KVL + 524288ull)           // k-hat f32 [b][h][l][64] (0.125 folded)
#define OFF_GVL    (OFF_KHAT + 524288ull)          // vl f32 [b][h][l][64]

// ---------------- dtype sniff ----------------
__global__ void k_sniff(const unsigned short* __restrict__ x, int* flag){
  int t = threadIdx.x;
  int m = 0;
  for (int i = t; i < 4096; i += 256){ int e = (x[i]>>7)&0xFF; m = (e>m)?e:m; }
  __shared__ int red[256];
  red[t] = m; __syncthreads();
  for (int s = 128; s > 0; s >>= 1){ if (t < s) red[t] = (red[t+s]>red[t])?red[t+s]:red[t]; __syncthreads(); }
  if (t == 0) flag[0] = (red[0] > 150) ? 1 : 0;   // 1 => fp32 inputs, 0 => bf16 inputs
}

// convert (or copy) a weight array to bf16
__global__ __launch_bounds__(256) void k_cvt(const void* __restrict__ src, unsigned short* __restrict__ dst,
                                             int n, const int* __restrict__ flag){
  int base = (blockIdx.x*256 + threadIdx.x)*8;
  if (base >= n) return;
  if (*flag){
    const float* s = (const float*)src + base;
    float4 v0 = *(const float4*)(s);
    float4 v1 = *(const float4*)(s+4);
    unsigned short tmp[8] __attribute__((aligned(16)));
    tmp[0]=f2bf(v0.x); tmp[1]=f2bf(v0.y); tmp[2]=f2bf(v0.z); tmp[3]=f2bf(v0.w);
    tmp[4]=f2bf(v1.x); tmp[5]=f2bf(v1.y); tmp[6]=f2bf(v1.z); tmp[7]=f2bf(v1.w);
    *(short8_t*)&dst[base] = *(short8_t*)tmp;
  } else {
    *(short8_t*)&dst[base] = *(const short8_t*)((const unsigned short*)src + base);
  }
}

// convert to f32 (latents, bias)
__global__ void k_cvtf(const void* __restrict__ src, float* __restrict__ dst, int n, const int* __restrict__ flag){
  int i = blockIdx.x*256 + threadIdx.x;
  if (i >= n) return;
  dst[i] = (*flag) ? ((const float*)src)[i] : bf2f(((const unsigned short*)src)[i]);
}

// ---------------- transpose x[b][c][n] -> xT[b][n][c] (bf16) ----------------
__global__ __launch_bounds__(256) void k_xt(const void* __restrict__ xraw, unsigned short* __restrict__ xT,
                                            const int* __restrict__ flag){
  int nb = blockIdx.x, cb = blockIdx.y, b = blockIdx.z;
  int n0 = nb*64, c0 = cb*64;
  __shared__ unsigned short tile[64][72];   // XOR-swizzled columns: col = n ^ (((row>>3)&7)<<3)
  int t = threadIdx.x;
  if (*flag){
    const float* xp = (const float*)xraw;
#pragma unroll
    for (int i = 0; i < 4; ++i){
      int ch = i*256 + t; int c = ch>>4, n4 = (ch&15)*4;
      float4 v = *(const float4*)&xp[((size_t)(b*512 + c0 + c))*4096 + n0 + n4];
      int cc = n4 ^ (((c>>3)&7)<<3);
      tile[c][cc+0]=f2bf(v.x); tile[c][cc+1]=f2bf(v.y); tile[c][cc+2]=f2bf(v.z); tile[c][cc+3]=f2bf(v.w);
    }
  } else {
    const unsigned short* xp = (const unsigned short*)xraw;
#pragma unroll
    for (int i = 0; i < 2; ++i){
      int ch = i*256 + t; int c = ch>>3, n8 = (ch&7)*8;
      *(short8_t*)&tile[c][n8 ^ (((c>>3)&7)<<3)] =
        *(const short8_t*)&xp[((size_t)(b*512 + c0 + c))*4096 + n0 + n8];
    }
  }
  __syncthreads();
#pragma unroll
  for (int i = 0; i < 2; ++i){
    int ch = i*256 + t; int n = ch>>3, c8 = (ch&7)*8;
    unsigned short tmp[8] __attribute__((aligned(16)));
#pragma unroll
    for (int j = 0; j < 8; ++j){
      int c = c8 + j;
      tmp[j] = tile[c][n ^ (((c>>3)&7)<<3)];
    }
    *(short8_t*)&xT[((size_t)(b*4096 + n0 + n))*512 + c0 + c8] = *(short8_t*)tmp;
  }
}

// ---------------- ql = w_q_lat @ latents (batch-independent), f32 ----------------
__global__ __launch_bounds__(256) void k_ql(const unsigned short* __restrict__ wqlat,
                                            const float* __restrict__ latf, float* __restrict__ ql){
  int o0 = blockIdx.x*64;
  extern __shared__ char smr[];
  float* latb = (float*)smr;                         // [128][16]
  unsigned short* wt = (unsigned short*)(smr + 8192); // [64][136]
  int t = threadIdx.x;
  int o = t>>2, l4 = (t&3)*4;
  float acc[4] = {0.f,0.f,0.f,0.f};
  for (int kk = 0; kk < 512; kk += 128){
    __syncthreads();
#pragma unroll
    for (int j = 0; j < 8; ++j){ int i = j*256 + t; latb[i] = latf[kk*16 + i]; }
#pragma unroll
    for (int j = 0; j < 4; ++j){ int ch = j*256 + t; int r = ch>>4, kc = (ch&15)*8;
      *(short8_t*)&wt[r*136 + kc] = *(const short8_t*)&wqlat[(size_t)(o0+r)*512 + kk + kc]; }
    __syncthreads();
    for (int k = 0; k < 128; ++k){
      float w = bf2f(wt[o*136 + k]);
      const float* lr = &latb[k*16 + l4];
#pragma unroll
      for (int j = 0; j < 4; ++j) acc[j] += w*lr[j];
    }
  }
#pragma unroll
  for (int j = 0; j < 4; ++j) ql[(o0+o)*16 + l4 + j] = acc[j];
}

// normalize ql over d per (h,l) -> qlhat [h][l][64] with 0.125 folded
__global__ void k_qlnorm(const float* __restrict__ ql, float* __restrict__ qlh){
  int l = blockIdx.x, h = blockIdx.y, d = threadIdx.x;
  float v = ql[(h*64 + d)*16 + l];
  float ss = v*v;
  for (int off = 32; off; off >>= 1) ss += __shfl_xor(ss, off);
  qlh[(h*16 + l)*64 + d] = 0.125f * v / fmaxf(sqrtf(ss), 1e-12f);
}

// ---------------- 128x128 MFMA GEMM core, K=512, 4 waves (2x2 quadrants of 64x64) ----------------
// A rows 0-63 from Ap0, 64-127 from Ap1 (both row-stride 512, k contiguous). B rows from Bp.
// acc[mt][nt]: D rows wm*64+mt*16+lq*4+r, cols wn*64+nt*16+lr.
DEV void gemm128(const unsigned short* __restrict__ Ap0, const unsigned short* __restrict__ Ap1,
                 const unsigned short* __restrict__ Bp,
                 unsigned short* At, unsigned short* Bt, floatx4 (&acc)[4][4]){
  int t = threadIdx.x, lane = t&63, wave = t>>6;
  int wm = wave>>1, wn = wave&1, lr = lane&15, lq = lane>>4;
  for (int kk = 0; kk < 512; kk += 64){
    __syncthreads();
#pragma unroll
    for (int i = 0; i < 4; ++i){
      int ch = i*256 + t; int r = ch>>3, kc = (ch&7)*8;
      const unsigned short* ap = (i < 2) ? (Ap0 + (size_t)r*512) : (Ap1 + (size_t)(r-64)*512);
      *(short8_t*)&At[r*72 + kc] = *(const short8_t*)&ap[kk + kc];
    }
#pragma unroll
    for (int i = 0; i < 4; ++i){
      int ch = i*256 + t; int r = ch>>3, kc = (ch&7)*8;
      *(short8_t*)&Bt[r*72 + kc] = *(const short8_t*)&Bp[(size_t)r*512 + kk + kc];
    }
    __syncthreads();
#pragma unroll
    for (int ks = 0; ks < 2; ++ks){
      bf16x8 a[4], b[4];
#pragma unroll
      for (int mt = 0; mt < 4; ++mt) a[mt] = *(const bf16x8*)&At[(wm*64 + mt*16 + lr)*72 + ks*32 + lq*8];
#pragma unroll
      for (int nt = 0; nt < 4; ++nt) b[nt] = *(const bf16x8*)&Bt[(wn*64 + nt*16 + lr)*72 + ks*32 + lq*8];
#pragma unroll
      for (int mt = 0; mt < 4; ++mt)
#pragma unroll
        for (int nt = 0; nt < 4; ++nt)
          acc[mt][nt] = __builtin_amdgcn_mfma_f32_16x16x32_bf16(a[mt], b[nt], acc[mt][nt], 0, 0, 0);
    }
  }
  __syncthreads();
}

// ---------------- fused kv-GEMM + attn1: M-tile = [k_h(64); v_h(64)], N=128 positions ----------------
__global__ __launch_bounds__(256) void k_kvattn1(const unsigned short* __restrict__ wkvx,
                                                 const unsigned short* __restrict__ xT,
                                                 const float* __restrict__ qlh2,
                                                 float* __restrict__ gnum, float* __restrict__ gden){
  int nb = blockIdx.x, h = blockIdx.y, b = blockIdx.z;
  int n0 = nb*128;
  extern __shared__ char smr[];
  unsigned short* At  = (unsigned short*)smr;            // [128][72] = 18432
  unsigned short* Bt  = At + 128*72;                     // [128][72] -> 36864
  unsigned short* kt  = At;                              // reuse: [128 n][72] k-hat (d contiguous)
  unsigned short* vt  = Bt;                              // reuse: [64 d][136] (17408 B)
  unsigned short* qls = (unsigned short*)(smr + 36864);  // [16 l][72] 0.125*q-hat -> 39168
  float* ssq  = (float*)(smr + 39168);                   // [128] rinv -> 39680
  float* wred = (float*)(smr + 39680);                   // [4][16]   -> 39936
  unsigned short* pt  = (unsigned short*)(smr + 39936);  // [16 l][136] p bf16 -> 44288
  int t = threadIdx.x, lane = t&63, wave = t>>6;
  int wm = wave>>1, wn = wave&1, lr = lane&15, lq = lane>>4;
  floatx4 acc[4][4];
  floatx4 zero = {0.f,0.f,0.f,0.f};
#pragma unroll
  for (int i = 0; i < 4; ++i) for (int j = 0; j < 4; ++j) acc[i][j] = zero;
  gemm128(wkvx + (size_t)(h*64)*512, wkvx + (size_t)(512 + h*64)*512,
          xT + ((size_t)(b*4096 + n0))*512, At, Bt, acc);
  // stage 0.125*q-hat [16][72]
  for (int i = t; i < 1024; i += 256) qls[(i>>6)*72 + (i&63)] = f2bf(qlh2[(size_t)h*1024 + i]);
  if (wm == 0){
    // k column inverse norms from f32 accumulators
#pragma unroll
    for (int nt = 0; nt < 4; ++nt){
      float s = 0.f;
#pragma unroll
      for (int mt = 0; mt < 4; ++mt)
#pragma unroll
        for (int r = 0; r < 4; ++r) s += acc[mt][nt][r]*acc[mt][nt][r];
      s += __shfl_xor(s, 16); s += __shfl_xor(s, 32);
      if (lq == 0) ssq[wn*64 + nt*16 + lr] = 1.f / fmaxf(sqrtf(s), 1e-12f);
    }
  } else {
    // v tile to LDS [d][n]
#pragma unroll
    for (int mt = 0; mt < 4; ++mt)
#pragma unroll
      for (int nt = 0; nt < 4; ++nt){
        int col = wn*64 + nt*16 + lr;
#pragma unroll
        for (int r = 0; r < 4; ++r) vt[(mt*16 + lq*4 + r)*136 + col] = f2bf(acc[mt][nt][r]);
      }
  }
  __syncthreads();
  if (wm == 0){
    // k-hat tile to LDS transposed [n][d], norm folded
#pragma unroll
    for (int nt = 0; nt < 4; ++nt){
      int col = wn*64 + nt*16 + lr;
      float rinv = ssq[col];
#pragma unroll
      for (int mt = 0; mt < 4; ++mt){
        unsigned short tmp[4] __attribute__((aligned(8)));
#pragma unroll
        for (int r = 0; r < 4; ++r) tmp[r] = f2bf(acc[mt][nt][r]*rinv);
        *(short4_t*)&kt[col*72 + mt*16 + lq*4] = *(short4_t*)tmp;
      }
    }
  }
  __syncthreads();
  // S^T[n][l] via MFMA: A = kt rows n, B = qls rows l, K=64
  floatx4 sl[2]; sl[0] = zero; sl[1] = zero;
#pragma unroll
  for (int ks = 0; ks < 2; ++ks){
    bf16x8 bb = *(const bf16x8*)&qls[lr*72 + ks*32 + lq*8];
#pragma unroll
    for (int i = 0; i < 2; ++i){
      bf16x8 aa = *(const bf16x8*)&kt[((wave*2 + i)*16 + lr)*72 + ks*32 + lq*8];
      sl[i] = __builtin_amdgcn_mfma_f32_16x16x32_bf16(aa, bb, sl[i], 0, 0, 0);
    }
  }
  // p = exp(s) (|s| <= 0.125); den partials; p to LDS [l][n]
  float dp = 0.f;
  float pv[2][4];
#pragma unroll
  for (int i = 0; i < 2; ++i)
#pragma unroll
    for (int r = 0; r < 4; ++r){ float p = __expf(sl[i][r]); pv[i][r] = p; dp += p; }
  dp += __shfl_xor(dp, 16); dp += __shfl_xor(dp, 32);
  if (lq == 0) wred[wave*16 + lr] = dp;
#pragma unroll
  for (int i = 0; i < 2; ++i){
    unsigned short tmp[4] __attribute__((aligned(8)));
#pragma unroll
    for (int r = 0; r < 4; ++r) tmp[r] = f2bf(pv[i][r]);
    *(short4_t*)&pt[lr*136 + (wave*2 + i)*16 + lq*4] = *(short4_t*)tmp;
  }
  __syncthreads();
  int bh = b*8 + h;
  if (t < 16) atomicAdd(&gden[bh*16 + t], wred[t] + wred[16+t] + wred[32+t] + wred[48+t]);
  // num^T[d][l] via MFMA: A = vt rows d (wave*16 block), B = pt rows l, K=128
  floatx4 nacc = zero;
#pragma unroll
  for (int ks = 0; ks < 4; ++ks){
    bf16x8 aa = *(const bf16x8*)&vt[(wave*16 + lr)*136 + ks*32 + lq*8];
    bf16x8 bb = *(const bf16x8*)&pt[lr*136 + ks*32 + lq*8];
    nacc = __builtin_amdgcn_mfma_f32_16x16x32_bf16(aa, bb, nacc, 0, 0, 0);
  }
  float* gp = &gnum[((size_t)bh*16 + lr)*64 + wave*16 + lq*4];
#pragma unroll
  for (int r = 0; r < 4; ++r) atomicAdd(&gp[r], nacc[r]);
}

// ---------------- kvl = w_kv_lat @ (num/den), f32 [b][o][l] ----------------
__global__ __launch_bounds__(256) void k_kvl(const unsigned short* __restrict__ wkvl,
                                             const float* __restrict__ gnum, const float* __restrict__ gden,
                                             float* __restrict__ kvl){
  int ob = blockIdx.x, b = blockIdx.y;
  extern __shared__ char smr[];
  float* latb = (float*)smr;                         // [512][16]
  unsigned short* wt = (unsigned short*)(smr + 32768); // [16][136]
  int t = threadIdx.x;
  for (int i = t; i < 8192; i += 256){
    int c = i>>4, l = i&15;
    int h = c>>6, d = c&63;
    int bh = b*8 + h;
    latb[i] = gnum[((size_t)(bh*16 + l))*64 + d] / gden[bh*16 + l];
  }
  int o = t>>4, l = t&15;
  int o0 = ob*16;
  float acc = 0.f;
  for (int kk = 0; kk < 512; kk += 128){
    __syncthreads();
    { int r = t>>4, kc = (t&15)*8;
      *(short8_t*)&wt[r*136 + kc] = *(const short8_t*)&wkvl[(size_t)(o0+r)*512 + kk + kc]; }
    __syncthreads();
    for (int k = 0; k < 128; ++k) acc += bf2f(wt[o*136 + k]) * latb[(kk+k)*16 + l];
  }
  kvl[((size_t)(b*1024 + o0 + o))*16 + l] = acc;
}

// normalize kl per (b,h,l); khat gets 0.125 folded; gvl raw
__global__ void k_klnorm(const float* __restrict__ kvl, float* __restrict__ khat, float* __restrict__ gvl){
  int l = blockIdx.x, h = blockIdx.y, b = blockIdx.z, d = threadIdx.x;
  float kl = kvl[((size_t)(b*1024 + h*64 + d))*16 + l];
  float vl = kvl[((size_t)(b*1024 + 512 + h*64 + d))*16 + l];
  float ss = kl*kl;
  for (int off = 32; off; off >>= 1) ss += __shfl_xor(ss, off);
  float inv = 0.125f / fmaxf(sqrtf(ss), 1e-12f);
  size_t o = ((size_t)((b*8+h)*16 + l))*64 + d;
  khat[o] = kl*inv;
  gvl[o] = vl;
}

// ---------------- Mmat: M[b][c][h*16+l] = sum_d wproj[c][h*64+d] * vl[b][h][l][d] ----------------
__global__ __launch_bounds__(256) void k_mmat(const unsigned short* __restrict__ wproj,
                                              const float* __restrict__ gvl,
                                              unsigned short* __restrict__ Mg){
  int cb = blockIdx.x, h = blockIdx.y, b = blockIdx.z;
  __shared__ unsigned short wt[128*68];
  int t = threadIdx.x;
#pragma unroll
  for (int i = 0; i < 4; ++i){ int ch = i*256 + t; int c = ch>>3, d8 = (ch&7)*8;
    *(short8_t*)&wt[c*68 + d8] = *(const short8_t*)&wproj[(size_t)(cb*128 + c)*512 + h*64 + d8]; }
  int l = t&15, cq = t>>4;
  float v[64];
  const float* vp = &gvl[((size_t)(b*8+h)*16 + l)*64];
#pragma unroll
  for (int j = 0; j < 16; ++j){ float4 f = *(const float4*)&vp[j*4];
    v[j*4+0]=f.x; v[j*4+1]=f.y; v[j*4+2]=f.z; v[j*4+3]=f.w; }
  __syncthreads();
#pragma unroll
  for (int c8 = 0; c8 < 8; ++c8){
    int c = cq*8 + c8;
    float dot = 0.f;
#pragma unroll
    for (int d = 0; d < 64; ++d) dot += bf2f(wt[c*68 + d]) * v[d];
    Mg[((size_t)(b*512) + cb*128 + c)*128 + h*16 + l] = f2bf(dot);
  }
}

// ---------------- attn2 probs: 128x128 q-GEMM (2 heads) + MFMA dots + softmax -> P bf16 ----------------
__global__ __launch_bounds__(256) void k_attn2p2(const unsigned short* __restrict__ wqx,
                                                 const unsigned short* __restrict__ xT,
                                                 const float* __restrict__ khatg,
                                                 unsigned short* __restrict__ Pg){
  int nb = blockIdx.x, hp = blockIdx.y, b = blockIdx.z;
  int n0 = nb*128;
  extern __shared__ char smr[];
  unsigned short* At  = (unsigned short*)smr;            // [128][72]
  unsigned short* Bt  = At + 128*72;
  unsigned short* qt0 = At;                              // reuse: head hp*2   q-hat [128 n][72]
  unsigned short* qt1 = Bt;                              // reuse: head hp*2+1
  unsigned short* khs = (unsigned short*)(smr + 36864);  // [2][16][72] -> 41472
  float* ssq = (float*)(smr + 41472);                    // [2][128] rinv -> 42496
  int t = threadIdx.x, lane = t&63, wave = t>>6;
  int wm = wave>>1, wn = wave&1, lr = lane&15, lq = lane>>4;
  floatx4 acc[4][4];
  floatx4 zero = {0.f,0.f,0.f,0.f};
#pragma unroll
  for (int i = 0; i < 4; ++i) for (int j = 0; j < 4; ++j) acc[i][j] = zero;
  gemm128(wqx + (size_t)(hp*128)*512, wqx + (size_t)(hp*128 + 64)*512,
          xT + ((size_t)(b*4096 + n0))*512, At, Bt, acc);
  // stage k-hat (0.125 folded) for both heads
  for (int i = t; i < 2048; i += 256){
    int hh = i>>10, rem = i&1023;
    khs[hh*1152 + (rem>>6)*72 + (rem&63)] = f2bf(khatg[((size_t)(b*8 + hp*2 + hh))*1024 + rem]);
  }
  // per-head column inverse norms (wave wm covers head wm's 64 rows)
#pragma unroll
  for (int nt = 0; nt < 4; ++nt){
    float s = 0.f;
#pragma unroll
    for (int mt = 0; mt < 4; ++mt)
#pragma unroll
      for (int r = 0; r < 4; ++r) s += acc[mt][nt][r]*acc[mt][nt][r];
    s += __shfl_xor(s, 16); s += __shfl_xor(s, 32);
    if (lq == 0) ssq[wm*128 + wn*64 + nt*16 + lr] = 1.f / fmaxf(sqrtf(s), 1e-12f);
  }
  __syncthreads();
  // q-hat tiles to LDS transposed [n][d], norm folded
  unsigned short* qtr = wm ? qt1 : qt0;
#pragma unroll
  for (int nt = 0; nt < 4; ++nt){
    int col = wn*64 + nt*16 + lr;
    float rinv = ssq[wm*128 + col];
#pragma unroll
    for (int mt = 0; mt < 4; ++mt){
      unsigned short tmp[4] __attribute__((aligned(8)));
#pragma unroll
      for (int r = 0; r < 4; ++r) tmp[r] = f2bf(acc[mt][nt][r]*rinv);
      *(short4_t*)&qtr[col*72 + mt*16 + lq*4] = *(short4_t*)tmp;
    }
  }
  __syncthreads();
  // S^T[n][l]: wave handles head wm, n-half wn (4 m-tiles), K=64
  floatx4 sl[4];
#pragma unroll
  for (int i = 0; i < 4; ++i) sl[i] = zero;
#pragma unroll
  for (int ks = 0; ks < 2; ++ks){
    bf16x8 bb = *(const bf16x8*)&khs[wm*1152 + lr*72 + ks*32 + lq*8];
#pragma unroll
    for (int i = 0; i < 4; ++i){
      bf16x8 aa = *(const bf16x8*)&qtr[((wn*4 + i)*16 + lr)*72 + ks*32 + lq*8];
      sl[i] = __builtin_amdgcn_mfma_f32_16x16x32_bf16(aa, bb, sl[i], 0, 0, 0);
    }
  }
  int h = hp*2 + wm;
#pragma unroll
  for (int i = 0; i < 4; ++i){
    float p[4], s[4];
#pragma unroll
    for (int r = 0; r < 4; ++r){ p[r] = __expf(sl[i][r]); s[r] = p[r]; }
#pragma unroll
    for (int r = 0; r < 4; ++r){
      s[r] += __shfl_xor(s[r], 1);
      s[r] += __shfl_xor(s[r], 2);
      s[r] += __shfl_xor(s[r], 4);
      s[r] += __shfl_xor(s[r], 8);
    }
    int nbase = wn*64 + i*16 + lq*4;
#pragma unroll
    for (int r = 0; r < 4; ++r)
      Pg[((size_t)(b*4096 + n0 + nbase + r))*128 + h*16 + lr] = f2bf(p[r]/s[r]);
  }
}

// ---------------- out = M @ P + bias: 64x128 tile, K=128 ----------------
__global__ __launch_bounds__(256) void k_out(const unsigned short* __restrict__ Mg,
                                             const unsigned short* __restrict__ Pg,
                                             const float* __restrict__ biasf,
                                             void* __restrict__ outv, const int* __restrict__ flag){
  int nb = blockIdx.x, cb = blockIdx.y, b = blockIdx.z;
  int n0 = nb*128, c0 = cb*64;
  extern __shared__ char smr[];
  unsigned short* At = (unsigned short*)smr;   // [64][136]
  unsigned short* Bt = At + 64*136;            // [128][136]
  int t = threadIdx.x, lane = t&63, wave = t>>6;
  int wm = wave>>1, wn = wave&1, lr = lane&15, lq = lane>>4;
#pragma unroll
  for (int i = 0; i < 4; ++i){ int ch = i*256 + t; int r = ch>>4, p8 = (ch&15)*8;
    *(short8_t*)&At[r*136 + p8] = *(const short8_t*)&Mg[((size_t)(b*512 + c0 + r))*128 + p8]; }
#pragma unroll
  for (int i = 0; i < 8; ++i){ int ch = i*256 + t; int r = ch>>4, p8 = (ch&15)*8;
    *(short8_t*)&Bt[r*136 + p8] = *(const short8_t*)&Pg[((size_t)(b*4096 + n0 + r))*128 + p8]; }
  __syncthreads();
  floatx4 acc[2][4];
  floatx4 zero = {0.f,0.f,0.f,0.f};
#pragma unroll
  for (int i = 0; i < 2; ++i) for (int j = 0; j < 4; ++j) acc[i][j] = zero;
#pragma unroll
  for (int ks = 0; ks < 4; ++ks){
    bf16x8 a0 = *(const bf16x8*)&At[(wm*32 + lr)*136 + ks*32 + lq*8];
    bf16x8 a1 = *(const bf16x8*)&At[(wm*32 + 16 + lr)*136 + ks*32 + lq*8];
#pragma unroll
    for (int nt = 0; nt < 4; ++nt){
      bf16x8 bb = *(const bf16x8*)&Bt[(wn*64 + nt*16 + lr)*136 + ks*32 + lq*8];
      acc[0][nt] = __builtin_amdgcn_mfma_f32_16x16x32_bf16(a0, bb, acc[0][nt], 0, 0, 0);
      acc[1][nt] = __builtin_amdgcn_mfma_f32_16x16x32_bf16(a1, bb, acc[1][nt], 0, 0, 0);
    }
  }
  __syncthreads();
  float* ct = (float*)smr;  // [64][132] f32
#pragma unroll
  for (int mt = 0; mt < 2; ++mt)
#pragma unroll
    for (int nt = 0; nt < 4; ++nt)
#pragma unroll
      for (int r = 0; r < 4; ++r){
        int row = wm*32 + mt*16 + lq*4 + r;
        ct[row*132 + wn*64 + nt*16 + lr] = acc[mt][nt][r] + biasf[c0 + row];
      }
  __syncthreads();
  if (*flag){
    float* of = (float*)outv;
#pragma unroll
    for (int i = 0; i < 8; ++i){ int ch = i*256 + t; int r = ch>>5, c4 = (ch&31)*4;
      *(float4*)&of[((size_t)(b*512 + c0 + r))*4096 + n0 + c4] = *(float4*)&ct[r*132 + c4]; }
  } else {
    unsigned short* ob = (unsigned short*)outv;
#pragma unroll
    for (int i = 0; i < 4; ++i){ int ch = i*256 + t; int r = ch>>4, c8 = (ch&15)*8;
      unsigned short tmp[8] __attribute__((aligned(16)));
#pragma unroll
      for (int j = 0; j < 8; ++j) tmp[j] = f2bf(ct[r*132 + c8 + j]);
      *(short8_t*)&ob[((size_t)(b*512 + c0 + r))*4096 + n0 + c8] = *(short8_t*)tmp; }
  }
}

extern "C" void kernel_launch(void* const* d_in, const int* in_sizes, int n_in,
                              void* d_out, int out_size, void* d_ws, size_t ws_size,
                              hipStream_t stream){
  (void)in_sizes; (void)n_in; (void)out_size; (void)ws_size;
  char* ws = (char*)d_ws;
  int* flag              = (int*)ws;
  unsigned short* xT     = (unsigned short*)(ws + OFF_XT);
  unsigned short* Pg     = (unsigned short*)(ws + OFF_KVX);              // [8][4096][128] bf16 = 8 MB
  unsigned short* Mg     = (unsigned short*)(ws + OFF_KVX + 8388608ull); // [8][512][128] bf16
  unsigned short* wkvx   = (unsigned short*)(ws + OFF_WKVX);
  unsigned short* wqx    = (unsigned short*)(ws + OFF_WQX);
  unsigned short* wkvl   = (unsigned short*)(ws + OFF_WKVL);
  unsigned short* wproj  = (unsigned short*)(ws + OFF_WPROJ);
  unsigned short* wqlat  = (unsigned short*)(ws + OFF_WQLAT);
  float* latf  = (float*)(ws + OFF_LATF);
  float* biasf = (float*)(ws + OFF_BIAS);
  float* ql    = (float*)(ws + OFF_QL);
  float* qlh   = (float*)(ws + OFF_QLH);
  float* gnum  = (float*)(ws + OFF_GNUM);
  float* gden  = (float*)(ws + OFF_GDEN);
  float* kvl   = (float*)(ws + OFF_KVL);
  float* khat  = (float*)(ws + OFF_KHAT);
  float* gvl   = (float*)(ws + OFF_GVL);

  k_sniff<<<1, 256, 0, stream>>>((const unsigned short*)d_in[0], flag);

  k_cvt<<<256, 256, 0, stream>>>(d_in[3], wkvx, 524288, flag);   // w_kv_x
  k_cvt<<<128, 256, 0, stream>>>(d_in[4], wqx,  262144, flag);   // w_q_x
  k_cvt<<<256, 256, 0, stream>>>(d_in[5], wkvl, 524288, flag);   // w_kv_lat
  k_cvt<<<128, 256, 0, stream>>>(d_in[6], wproj,262144, flag);   // w_proj
  k_cvt<<<128, 256, 0, stream>>>(d_in[2], wqlat,262144, flag);   // w_q_lat
  k_cvtf<<<32, 256, 0, stream>>>(d_in[1], latf, 8192, flag);     // latents
  k_cvtf<<<2, 256, 0, stream>>>(d_in[7], biasf, 512, flag);      // b_proj

  k_xt<<<dim3(64, 8, 8), 256, 0, stream>>>(d_in[0], xT, flag);

  k_ql<<<8, 256, 8192 + 64*136*2, stream>>>(wqlat, latf, ql);
  k_qlnorm<<<dim3(16, 8), 64, 0, stream>>>(ql, qlh);

  hipMemsetAsync(ws + OFF_GNUM, 0, 524288 + 4096, stream);       // gnum + gden

  k_kvattn1<<<dim3(32, 8, 8), 256, 44288, stream>>>(wkvx, xT, qlh, gnum, gden);
  k_kvl<<<dim3(64, 8), 256, 32768 + 16*136*2, stream>>>(wkvl, gnum, gden, kvl);
  k_klnorm<<<dim3(16, 8, 8), 64, 0, stream>>>(kvl, khat, gvl);
  k_mmat<<<dim3(4, 8, 8), 256, 0, stream>>>(wproj, gvl, Mg);
  k_attn2p2<<<dim3(32, 4, 8), 256, 42496, stream>>>(wqx, xT, khat, Pg);
  k_out<<<dim3(32, 8, 8), 256, 52224, stream>>>(Mg, Pg, biasf, d_out, flag);
}

// Round 4
// 310.516 us; speedup vs baseline: 1.3129x; 1.0137x over previous
//
#include <hip/hip_runtime.h>

// LatentMixer on MI355X. bf16-MFMA pipeline with runtime input-dtype sniffing.
// B=8, C=512, HW=4096, L=16, heads=8, d=64, scale=0.125, eps=1e-12.
// R2: out = (w_proj@blockdiag(V)) @ P + bias (algebraic fusion).
// R3: attn1 fused into kv-GEMM epilogue; 128x128 tiles.
// R4: global_load_lds width=16 staging (m97 ladder), unpadded LDS tiles; launch fusion.

typedef __bf16 bf16x8 __attribute__((ext_vector_type(8)));
typedef float floatx4 __attribute__((ext_vector_type(4)));
typedef short short8_t __attribute__((ext_vector_type(8)));
typedef short short4_t __attribute__((ext_vector_type(4)));

#define DEV __device__ __forceinline__

DEV float bf2f(unsigned short u){ union{unsigned int i; float f;} v; v.i = ((unsigned int)u)<<16; return v.f; }
DEV unsigned short f2bf(float f){
  union{float f; unsigned int i;} v; v.f = f;
  unsigned int i = v.i;
  return (unsigned short)((i + 0x7fffu + ((i>>16)&1u)) >> 16);
}

// async global->LDS, 16 B per lane; LDS dest = base + lane*16 (wave-uniform base!)
DEV void glds16(const void* g, void* l){
  __builtin_amdgcn_global_load_lds((const __attribute__((address_space(1))) void*)g,
                                   (__attribute__((address_space(3))) void*)l, 16, 0, 0);
}

// ---------------- workspace layout (bytes) ----------------
#define OFF_XT     256ull                          // xT bf16 [8][4096][512]
#define OFF_KVX    (OFF_XT + 33554432ull)          // region reused: Pg bf16 [8][4096][128] + Mg
#define OFF_WKVX   (OFF_KVX + 67108864ull)         // w_kv_x bf16   (weights contiguous from here)
#define OFF_WQX    (OFF_WKVX + 1048576ull)         // w_q_x bf16
#define OFF_WKVL   (OFF_WQX + 524288ull)           // w_kv_lat bf16
#define OFF_WPROJ  (OFF_WKVL + 1048576ull)         // w_proj bf16
#define OFF_WQLAT  (OFF_WPROJ + 524288ull)         // w_q_lat bf16
#define OFF_LATF   (OFF_WQLAT + 524288ull)         // latents f32 [512][16]
#define OFF_BIAS   (OFF_LATF + 32768ull)           // bias f32 [512]
#define OFF_QLH    (OFF_BIAS + 4096ull)            // ql-hat f32 [h][l][64] (0.125 folded)
#define OFF_GNUM   (OFF_QLH + 32768ull)            // attn1 numerator f32 [b][h][l][64]
#define OFF_GDEN   (OFF_GNUM + 524288ull)          // attn1 denominator f32 [b][h][l]
#define OFF_KVL    (OFF_GDEN + 4096ull)            // kvl f32 [b][1024][16]
#define OFF_KHAT   (OFF_KVL + 524288ull)           // k-hat f32 [b][h][l][64] (0.125 folded)
#define OFF_GVL    (OFF_KHAT + 524288ull)          // vl f32 [b][h][l][64]

// ---------------- dtype sniff ----------------
__global__ void k_sniff(const unsigned short* __restrict__ x, int* flag){
  int t = threadIdx.x;
  int m = 0;
  for (int i = t; i < 4096; i += 256){ int e = (x[i]>>7)&0xFF; m = (e>m)?e:m; }
  __shared__ int red[256];
  red[t] = m; __syncthreads();
  for (int s = 128; s > 0; s >>= 1){ if (t < s) red[t] = (red[t+s]>red[t])?red[t+s]:red[t]; __syncthreads(); }
  if (t == 0) flag[0] = (red[0] > 150) ? 1 : 0;   // 1 => fp32 inputs, 0 => bf16 inputs
}

// ---------------- fused prep: all 5 weight converts + latents + bias ----------------
// dst weights are contiguous in ws starting at OFF_WKVX in order kvx,qx,kvl,proj,qlat.
__global__ __launch_bounds__(256) void k_prep(const void* s0, const void* s1, const void* s2,
                                              const void* s3, const void* s4,
                                              const void* slat, const void* sbias,
                                              unsigned short* __restrict__ wdst,
                                              float* __restrict__ latf, float* __restrict__ biasf,
                                              const int* __restrict__ flag){
  int b = blockIdx.x, t = threadIdx.x;
  int isf = *flag;
  if (b < 896){
    int e = b*2048 + t*8;
    const void* src; int off;
    if (e < 524288)      { src = s0; off = e; }
    else if (e < 786432) { src = s1; off = e - 524288; }
    else if (e < 1310720){ src = s2; off = e - 786432; }
    else if (e < 1572864){ src = s3; off = e - 1310720; }
    else                 { src = s4; off = e - 1572864; }
    if (isf){
      const float* s = (const float*)src + off;
      float4 v0 = *(const float4*)(s);
      float4 v1 = *(const float4*)(s+4);
      unsigned short tmp[8] __attribute__((aligned(16)));
      tmp[0]=f2bf(v0.x); tmp[1]=f2bf(v0.y); tmp[2]=f2bf(v0.z); tmp[3]=f2bf(v0.w);
      tmp[4]=f2bf(v1.x); tmp[5]=f2bf(v1.y); tmp[6]=f2bf(v1.z); tmp[7]=f2bf(v1.w);
      *(short8_t*)&wdst[e] = *(short8_t*)tmp;
    } else {
      *(short8_t*)&wdst[e] = *(const short8_t*)((const unsigned short*)src + off);
    }
  } else if (b < 900){
    int i = (b-896)*2048 + t*8;
#pragma unroll
    for (int j = 0; j < 8; ++j)
      latf[i+j] = isf ? ((const float*)slat)[i+j] : bf2f(((const unsigned short*)slat)[i+j]);
  } else {
    if (t < 512) biasf[t] = isf ? ((const float*)sbias)[t] : bf2f(((const unsigned short*)sbias)[t]);
  }
}

// ---------------- transpose x[b][c][n] -> xT[b][n][c] (bf16) ----------------
__global__ __launch_bounds__(256) void k_xt(const void* __restrict__ xraw, unsigned short* __restrict__ xT,
                                            const int* __restrict__ flag){
  int nb = blockIdx.x, cb = blockIdx.y, b = blockIdx.z;
  int n0 = nb*64, c0 = cb*64;
  __shared__ unsigned short tile[64][72];   // XOR-swizzled columns: col = n ^ (((row>>3)&7)<<3)
  int t = threadIdx.x;
  if (*flag){
    const float* xp = (const float*)xraw;
#pragma unroll
    for (int i = 0; i < 4; ++i){
      int ch = i*256 + t; int c = ch>>4, n4 = (ch&15)*4;
      float4 v = *(const float4*)&xp[((size_t)(b*512 + c0 + c))*4096 + n0 + n4];
      int cc = n4 ^ (((c>>3)&7)<<3);
      tile[c][cc+0]=f2bf(v.x); tile[c][cc+1]=f2bf(v.y); tile[c][cc+2]=f2bf(v.z); tile[c][cc+3]=f2bf(v.w);
    }
  } else {
    const unsigned short* xp = (const unsigned short*)xraw;
#pragma unroll
    for (int i = 0; i < 2; ++i){
      int ch = i*256 + t; int c = ch>>3, n8 = (ch&7)*8;
      *(short8_t*)&tile[c][n8 ^ (((c>>3)&7)<<3)] =
        *(const short8_t*)&xp[((size_t)(b*512 + c0 + c))*4096 + n0 + n8];
    }
  }
  __syncthreads();
#pragma unroll
  for (int i = 0; i < 2; ++i){
    int ch = i*256 + t; int n = ch>>3, c8 = (ch&7)*8;
    unsigned short tmp[8] __attribute__((aligned(16)));
#pragma unroll
    for (int j = 0; j < 8; ++j){
      int c = c8 + j;
      tmp[j] = tile[c][n ^ (((c>>3)&7)<<3)];
    }
    *(short8_t*)&xT[((size_t)(b*4096 + n0 + n))*512 + c0 + c8] = *(short8_t*)tmp;
  }
}

// ---------------- ql = w_q_lat @ latents + normalize -> qlhat [h][l][64], 0.125 folded ----------------
__global__ __launch_bounds__(256) void k_ql(const unsigned short* __restrict__ wqlat,
                                            const float* __restrict__ latf, float* __restrict__ qlh){
  int h = blockIdx.x, o0 = h*64;
  extern __shared__ char smr[];
  float* latb = (float*)smr;                          // [128][16] = 8192
  unsigned short* wt = (unsigned short*)(smr + 8192); // [64][136] = 17408
  float* qbuf = (float*)(smr + 8192 + 17408);         // [64][16] = 4096
  float* rinv = (float*)(smr + 8192 + 17408 + 4096);  // [16]
  int t = threadIdx.x;
  int o = t>>2, l4 = (t&3)*4;
  float acc[4] = {0.f,0.f,0.f,0.f};
  for (int kk = 0; kk < 512; kk += 128){
    __syncthreads();
#pragma unroll
    for (int j = 0; j < 8; ++j){ int i = j*256 + t; latb[i] = latf[kk*16 + i]; }
#pragma unroll
    for (int j = 0; j < 4; ++j){ int ch = j*256 + t; int r = ch>>4, kc = (ch&15)*8;
      *(short8_t*)&wt[r*136 + kc] = *(const short8_t*)&wqlat[(size_t)(o0+r)*512 + kk + kc]; }
    __syncthreads();
    for (int k = 0; k < 128; ++k){
      float w = bf2f(wt[o*136 + k]);
      const float* lr = &latb[k*16 + l4];
#pragma unroll
      for (int j = 0; j < 4; ++j) acc[j] += w*lr[j];
    }
  }
#pragma unroll
  for (int j = 0; j < 4; ++j) qbuf[o*16 + l4 + j] = acc[j];
  __syncthreads();
  if (t < 16){
    float ss = 0.f;
    for (int oo = 0; oo < 64; ++oo){ float v = qbuf[oo*16 + t]; ss += v*v; }
    rinv[t] = 0.125f / fmaxf(sqrtf(ss), 1e-12f);
  }
  __syncthreads();
#pragma unroll
  for (int j = 0; j < 4; ++j) qlh[(h*16 + l4 + j)*64 + o] = acc[j]*rinv[l4 + j];
}

// ---------------- 128x128 MFMA GEMM core, K=512, global_load_lds staging ----------------
// LDS: At [128][64] shorts (16384 B) at smr, Bt [128][64] at smr+16384. UNPADDED (glld requires).
// A rows 0-63 from Ap0, 64-127 from Ap1 (row stride 512 shorts). B rows from Bp.
// acc[mt][nt]: D rows wm*64+mt*16+lq*4+r, cols wn*64+nt*16+lr.
DEV void gemm128(const unsigned short* __restrict__ Ap0, const unsigned short* __restrict__ Ap1,
                 const unsigned short* __restrict__ Bp,
                 unsigned short* At, unsigned short* Bt, floatx4 (&acc)[4][4]){
  int t = threadIdx.x, lane = t&63, wave = t>>6;
  int wm = wave>>1, wn = wave&1, lr = lane&15, lq = lane>>4;
  int rsub = lane>>3;          // 0..7: row within 8-row chunk
  int koff = (lane&7)*8;       // shorts within row (16 B per lane)
  for (int kk = 0; kk < 512; kk += 64){
    __syncthreads();
#pragma unroll
    for (int c2 = 0; c2 < 4; ++c2){
      int chunk = wave*4 + c2;           // 0..15, wave-uniform
      int row = chunk*8 + rsub;
      const unsigned short* gp = (chunk < 8) ? (Ap0 + (size_t)row*512 + kk + koff)
                                             : (Ap1 + (size_t)(row-64)*512 + kk + koff);
      glds16(gp, At + chunk*512);
    }
#pragma unroll
    for (int c2 = 0; c2 < 4; ++c2){
      int chunk = wave*4 + c2;
      int row = chunk*8 + rsub;
      glds16(Bp + (size_t)row*512 + kk + koff, Bt + chunk*512);
    }
    __syncthreads();   // drains vmcnt (glld) before LDS reads
#pragma unroll
    for (int ks = 0; ks < 2; ++ks){
      bf16x8 a[4], b[4];
#pragma unroll
      for (int mt = 0; mt < 4; ++mt) a[mt] = *(const bf16x8*)&At[(wm*64 + mt*16 + lr)*64 + ks*32 + lq*8];
#pragma unroll
      for (int nt = 0; nt < 4; ++nt) b[nt] = *(const bf16x8*)&Bt[(wn*64 + nt*16 + lr)*64 + ks*32 + lq*8];
#pragma unroll
      for (int mt = 0; mt < 4; ++mt)
#pragma unroll
        for (int nt = 0; nt < 4; ++nt)
          acc[mt][nt] = __builtin_amdgcn_mfma_f32_16x16x32_bf16(a[mt], b[nt], acc[mt][nt], 0, 0, 0);
    }
  }
  __syncthreads();  // protects LDS reuse by epilogues
}

// ---------------- fused kv-GEMM + attn1: M-tile = [k_h(64); v_h(64)], N=128 positions ----------------
// LDS: staging 0..32768. Epilogue: kt [128][72] @0 (18432), vt [64][136] @18432 (17408 ->35840),
// qls [16][72] @35840 (2304 ->38144), ssq @38144 (512 ->38656), wred @38656 (256 ->38912),
// pt [16][136] @38912 (4352 ->43264). Total 43264.
__global__ __launch_bounds__(256) void k_kvattn1(const unsigned short* __restrict__ wkvx,
                                                 const unsigned short* __restrict__ xT,
                                                 const float* __restrict__ qlh2,
                                                 float* __restrict__ gnum, float* __restrict__ gden){
  int nb = blockIdx.x, h = blockIdx.y, b = blockIdx.z;
  int n0 = nb*128;
  extern __shared__ char smr[];
  unsigned short* At  = (unsigned short*)smr;
  unsigned short* Bt  = (unsigned short*)(smr + 16384);
  unsigned short* kt  = (unsigned short*)smr;            // [128 n][72] k-hat, d contiguous
  unsigned short* vt  = (unsigned short*)(smr + 18432);  // [64 d][136]
  unsigned short* qls = (unsigned short*)(smr + 35840);  // [16 l][72] 0.125*q-hat
  float* ssq  = (float*)(smr + 38144);                   // [128] rinv
  float* wred = (float*)(smr + 38656);                   // [4][16]
  unsigned short* pt  = (unsigned short*)(smr + 38912);  // [16 l][136] p bf16
  int t = threadIdx.x, lane = t&63, wave = t>>6;
  int wm = wave>>1, wn = wave&1, lr = lane&15, lq = lane>>4;
  floatx4 acc[4][4];
  floatx4 zero = {0.f,0.f,0.f,0.f};
#pragma unroll
  for (int i = 0; i < 4; ++i) for (int j = 0; j < 4; ++j) acc[i][j] = zero;
  gemm128(wkvx + (size_t)(h*64)*512, wkvx + (size_t)(512 + h*64)*512,
          xT + ((size_t)(b*4096 + n0))*512, At, Bt, acc);
  // stage 0.125*q-hat [16][72]
  for (int i = t; i < 1024; i += 256) qls[(i>>6)*72 + (i&63)] = f2bf(qlh2[(size_t)h*1024 + i]);
  if (wm == 0){
    // k column inverse norms from f32 accumulators
#pragma unroll
    for (int nt = 0; nt < 4; ++nt){
      float s = 0.f;
#pragma unroll
      for (int mt = 0; mt < 4; ++mt)
#pragma unroll
        for (int r = 0; r < 4; ++r) s += acc[mt][nt][r]*acc[mt][nt][r];
      s += __shfl_xor(s, 16); s += __shfl_xor(s, 32);
      if (lq == 0) ssq[wn*64 + nt*16 + lr] = 1.f / fmaxf(sqrtf(s), 1e-12f);
    }
  } else {
    // v tile to LDS [d][n]
#pragma unroll
    for (int mt = 0; mt < 4; ++mt)
#pragma unroll
      for (int nt = 0; nt < 4; ++nt){
        int col = wn*64 + nt*16 + lr;
#pragma unroll
        for (int r = 0; r < 4; ++r) vt[(mt*16 + lq*4 + r)*136 + col] = f2bf(acc[mt][nt][r]);
      }
  }
  __syncthreads();
  if (wm == 0){
    // k-hat tile to LDS transposed [n][d], norm folded
#pragma unroll
    for (int nt = 0; nt < 4; ++nt){
      int col = wn*64 + nt*16 + lr;
      float rinv = ssq[col];
#pragma unroll
      for (int mt = 0; mt < 4; ++mt){
        unsigned short tmp[4] __attribute__((aligned(8)));
#pragma unroll
        for (int r = 0; r < 4; ++r) tmp[r] = f2bf(acc[mt][nt][r]*rinv);
        *(short4_t*)&kt[col*72 + mt*16 + lq*4] = *(short4_t*)tmp;
      }
    }
  }
  __syncthreads();
  // S^T[n][l] via MFMA: A = kt rows n, B = qls rows l, K=64
  floatx4 sl[2]; sl[0] = zero; sl[1] = zero;
#pragma unroll
  for (int ks = 0; ks < 2; ++ks){
    bf16x8 bb = *(const bf16x8*)&qls[lr*72 + ks*32 + lq*8];
#pragma unroll
    for (int i = 0; i < 2; ++i){
      bf16x8 aa = *(const bf16x8*)&kt[((wave*2 + i)*16 + lr)*72 + ks*32 + lq*8];
      sl[i] = __builtin_amdgcn_mfma_f32_16x16x32_bf16(aa, bb, sl[i], 0, 0, 0);
    }
  }
  // p = exp(s) (|s| <= 0.125); den partials; p to LDS [l][n]
  float dp = 0.f;
  float pv[2][4];
#pragma unroll
  for (int i = 0; i < 2; ++i)
#pragma unroll
    for (int r = 0; r < 4; ++r){ float p = __expf(sl[i][r]); pv[i][r] = p; dp += p; }
  dp += __shfl_xor(dp, 16); dp += __shfl_xor(dp, 32);
  if (lq == 0) wred[wave*16 + lr] = dp;
#pragma unroll
  for (int i = 0; i < 2; ++i){
    unsigned short tmp[4] __attribute__((aligned(8)));
#pragma unroll
    for (int r = 0; r < 4; ++r) tmp[r] = f2bf(pv[i][r]);
    *(short4_t*)&pt[lr*136 + (wave*2 + i)*16 + lq*4] = *(short4_t*)tmp;
  }
  __syncthreads();
  int bh = b*8 + h;
  if (t < 16) atomicAdd(&gden[bh*16 + t], wred[t] + wred[16+t] + wred[32+t] + wred[48+t]);
  // num^T[d][l] via MFMA: A = vt rows d (wave*16 block), B = pt rows l, K=128
  floatx4 nacc = zero;
#pragma unroll
  for (int ks = 0; ks < 4; ++ks){
    bf16x8 aa = *(const bf16x8*)&vt[(wave*16 + lr)*136 + ks*32 + lq*8];
    bf16x8 bb = *(const bf16x8*)&pt[lr*136 + ks*32 + lq*8];
    nacc = __builtin_amdgcn_mfma_f32_16x16x32_bf16(aa, bb, nacc, 0, 0, 0);
  }
  float* gp = &gnum[((size_t)bh*16 + lr)*64 + wave*16 + lq*4];
#pragma unroll
  for (int r = 0; r < 4; ++r) atomicAdd(&gp[r], nacc[r]);
}

// ---------------- kvl = w_kv_lat @ (num/den), f32 [b][o][l] ----------------
__global__ __launch_bounds__(256) void k_kvl(const unsigned short* __restrict__ wkvl,
                                             const float* __restrict__ gnum, const float* __restrict__ gden,
                                             float* __restrict__ kvl){
  int ob = blockIdx.x, b = blockIdx.y;
  extern __shared__ char smr[];
  float* latb = (float*)smr;                         // [512][16]
  unsigned short* wt = (unsigned short*)(smr + 32768); // [16][136]
  int t = threadIdx.x;
  for (int i = t; i < 8192; i += 256){
    int c = i>>4, l = i&15;
    int h = c>>6, d = c&63;
    int bh = b*8 + h;
    latb[i] = gnum[((size_t)(bh*16 + l))*64 + d] / gden[bh*16 + l];
  }
  int o = t>>4, l = t&15;
  int o0 = ob*16;
  float acc = 0.f;
  for (int kk = 0; kk < 512; kk += 128){
    __syncthreads();
    { int r = t>>4, kc = (t&15)*8;
      *(short8_t*)&wt[r*136 + kc] = *(const short8_t*)&wkvl[(size_t)(o0+r)*512 + kk + kc]; }
    __syncthreads();
    for (int k = 0; k < 128; ++k) acc += bf2f(wt[o*136 + k]) * latb[(kk+k)*16 + l];
  }
  kvl[((size_t)(b*1024 + o0 + o))*16 + l] = acc;
}

// normalize kl per (b,h,l); khat gets 0.125 folded; gvl raw
__global__ void k_klnorm(const float* __restrict__ kvl, float* __restrict__ khat, float* __restrict__ gvl){
  int l = blockIdx.x, h = blockIdx.y, b = blockIdx.z, d = threadIdx.x;
  float kl = kvl[((size_t)(b*1024 + h*64 + d))*16 + l];
  float vl = kvl[((size_t)(b*1024 + 512 + h*64 + d))*16 + l];
  float ss = kl*kl;
  for (int off = 32; off; off >>= 1) ss += __shfl_xor(ss, off);
  float inv = 0.125f / fmaxf(sqrtf(ss), 1e-12f);
  size_t o = ((size_t)((b*8+h)*16 + l))*64 + d;
  khat[o] = kl*inv;
  gvl[o] = vl;
}

// ---------------- Mmat: M[b][c][h*16+l] = sum_d wproj[c][h*64+d] * vl[b][h][l][d] ----------------
__global__ __launch_bounds__(256) void k_mmat(const unsigned short* __restrict__ wproj,
                                              const float* __restrict__ gvl,
                                              unsigned short* __restrict__ Mg){
  int cb = blockIdx.x, h = blockIdx.y, b = blockIdx.z;
  __shared__ unsigned short wt[128*68];
  int t = threadIdx.x;
#pragma unroll
  for (int i = 0; i < 4; ++i){ int ch = i*256 + t; int c = ch>>3, d8 = (ch&7)*8;
    *(short8_t*)&wt[c*68 + d8] = *(const short8_t*)&wproj[(size_t)(cb*128 + c)*512 + h*64 + d8]; }
  int l = t&15, cq = t>>4;
  float v[64];
  const float* vp = &gvl[((size_t)(b*8+h)*16 + l)*64];
#pragma unroll
  for (int j = 0; j < 16; ++j){ float4 f = *(const float4*)&vp[j*4];
    v[j*4+0]=f.x; v[j*4+1]=f.y; v[j*4+2]=f.z; v[j*4+3]=f.w; }
  __syncthreads();
#pragma unroll
  for (int c8 = 0; c8 < 8; ++c8){
    int c = cq*8 + c8;
    float dot = 0.f;
#pragma unroll
    for (int d = 0; d < 64; ++d) dot += bf2f(wt[c*68 + d]) * v[d];
    Mg[((size_t)(b*512) + cb*128 + c)*128 + h*16 + l] = f2bf(dot);
  }
}

// ---------------- attn2 probs: 128x128 q-GEMM (2 heads) + MFMA dots + softmax -> P bf16 ----------------
// LDS: staging 0..32768. Epilogue: qt0 [128][72] @0, qt1 @18432 (->36864),
// khs [2][16][72] @36864 (->41472), ssq [2][128] @41472 (->42496). Total 42496.
__global__ __launch_bounds__(256) void k_attn2p2(const unsigned short* __restrict__ wqx,
                                                 const unsigned short* __restrict__ xT,
                                                 const float* __restrict__ khatg,
                                                 unsigned short* __restrict__ Pg){
  int nb = blockIdx.x, hp = blockIdx.y, b = blockIdx.z;
  int n0 = nb*128;
  extern __shared__ char smr[];
  unsigned short* At  = (unsigned short*)smr;
  unsigned short* Bt  = (unsigned short*)(smr + 16384);
  unsigned short* qt0 = (unsigned short*)smr;            // head hp*2   q-hat [128 n][72]
  unsigned short* qt1 = (unsigned short*)(smr + 18432);  // head hp*2+1
  unsigned short* khs = (unsigned short*)(smr + 36864);  // [2][16][72]
  float* ssq = (float*)(smr + 41472);                    // [2][128] rinv
  int t = threadIdx.x, lane = t&63, wave = t>>6;
  int wm = wave>>1, wn = wave&1, lr = lane&15, lq = lane>>4;
  floatx4 acc[4][4];
  floatx4 zero = {0.f,0.f,0.f,0.f};
#pragma unroll
  for (int i = 0; i < 4; ++i) for (int j = 0; j < 4; ++j) acc[i][j] = zero;
  gemm128(wqx + (size_t)(hp*128)*512, wqx + (size_t)(hp*128 + 64)*512,
          xT + ((size_t)(b*4096 + n0))*512, At, Bt, acc);
  // stage k-hat (0.125 folded) for both heads
  for (int i = t; i < 2048; i += 256){
    int hh = i>>10, rem = i&1023;
    khs[hh*1152 + (rem>>6)*72 + (rem&63)] = f2bf(khatg[((size_t)(b*8 + hp*2 + hh))*1024 + rem]);
  }
  // per-head column inverse norms (wave wm covers head wm's 64 rows)
#pragma unroll
  for (int nt = 0; nt < 4; ++nt){
    float s = 0.f;
#pragma unroll
    for (int mt = 0; mt < 4; ++mt)
#pragma unroll
      for (int r = 0; r < 4; ++r) s += acc[mt][nt][r]*acc[mt][nt][r];
    s += __shfl_xor(s, 16); s += __shfl_xor(s, 32);
    if (lq == 0) ssq[wm*128 + wn*64 + nt*16 + lr] = 1.f / fmaxf(sqrtf(s), 1e-12f);
  }
  __syncthreads();
  // q-hat tiles to LDS transposed [n][d], norm folded
  unsigned short* qtr = wm ? qt1 : qt0;
#pragma unroll
  for (int nt = 0; nt < 4; ++nt){
    int col = wn*64 + nt*16 + lr;
    float rinv = ssq[wm*128 + col];
#pragma unroll
    for (int mt = 0; mt < 4; ++mt){
      unsigned short tmp[4] __attribute__((aligned(8)));
#pragma unroll
      for (int r = 0; r < 4; ++r) tmp[r] = f2bf(acc[mt][nt][r]*rinv);
      *(short4_t*)&qtr[col*72 + mt*16 + lq*4] = *(short4_t*)tmp;
    }
  }
  __syncthreads();
  // S^T[n][l]: wave handles head wm, n-half wn (4 m-tiles), K=64
  floatx4 sl[4];
#pragma unroll
  for (int i = 0; i < 4; ++i) sl[i] = zero;
  unsigned short* qsrc = wm ? qt1 : qt0;
#pragma unroll
  for (int ks = 0; ks < 2; ++ks){
    bf16x8 bb = *(const bf16x8*)&khs[wm*1152 + lr*72 + ks*32 + lq*8];
#pragma unroll
    for (int i = 0; i < 4; ++i){
      bf16x8 aa = *(const bf16x8*)&qsrc[((wn*4 + i)*16 + lr)*72 + ks*32 + lq*8];
      sl[i] = __builtin_amdgcn_mfma_f32_16x16x32_bf16(aa, bb, sl[i], 0, 0, 0);
    }
  }
  int h = hp*2 + wm;
#pragma unroll
  for (int i = 0; i < 4; ++i){
    float p[4], s[4];
#pragma unroll
    for (int r = 0; r < 4; ++r){ p[r] = __expf(sl[i][r]); s[r] = p[r]; }
#pragma unroll
    for (int r = 0; r < 4; ++r){
      s[r] += __shfl_xor(s[r], 1);
      s[r] += __shfl_xor(s[r], 2);
      s[r] += __shfl_xor(s[r], 4);
      s[r] += __shfl_xor(s[r], 8);
    }
    int nbase = wn*64 + i*16 + lq*4;
#pragma unroll
    for (int r = 0; r < 4; ++r)
      Pg[((size_t)(b*4096 + n0 + nbase + r))*128 + h*16 + lr] = f2bf(p[r]/s[r]);
  }
}

// ---------------- out = M @ P + bias: 64x128 tile, K=128 ----------------
__global__ __launch_bounds__(256) void k_out(const unsigned short* __restrict__ Mg,
                                             const unsigned short* __restrict__ Pg,
                                             const float* __restrict__ biasf,
                                             void* __restrict__ outv, const int* __restrict__ flag){
  int nb = blockIdx.x, cb = blockIdx.y, b = blockIdx.z;
  int n0 = nb*128, c0 = cb*64;
  extern __shared__ char smr[];
  unsigned short* At = (unsigned short*)smr;   // [64][136]
  unsigned short* Bt = At + 64*136;            // [128][136]
  int t = threadIdx.x, lane = t&63, wave = t>>6;
  int wm = wave>>1, wn = wave&1, lr = lane&15, lq = lane>>4;
#pragma unroll
  for (int i = 0; i < 4; ++i){ int ch = i*256 + t; int r = ch>>4, p8 = (ch&15)*8;
    *(short8_t*)&At[r*136 + p8] = *(const short8_t*)&Mg[((size_t)(b*512 + c0 + r))*128 + p8]; }
#pragma unroll
  for (int i = 0; i < 8; ++i){ int ch = i*256 + t; int r = ch>>4, p8 = (ch&15)*8;
    *(short8_t*)&Bt[r*136 + p8] = *(const short8_t*)&Pg[((size_t)(b*4096 + n0 + r))*128 + p8]; }
  __syncthreads();
  floatx4 acc[2][4];
  floatx4 zero = {0.f,0.f,0.f,0.f};
#pragma unroll
  for (int i = 0; i < 2; ++i) for (int j = 0; j < 4; ++j) acc[i][j] = zero;
#pragma unroll
  for (int ks = 0; ks < 4; ++ks){
    bf16x8 a0 = *(const bf16x8*)&At[(wm*32 + lr)*136 + ks*32 + lq*8];
    bf16x8 a1 = *(const bf16x8*)&At[(wm*32 + 16 + lr)*136 + ks*32 + lq*8];
#pragma unroll
    for (int nt = 0; nt < 4; ++nt){
      bf16x8 bb = *(const bf16x8*)&Bt[(wn*64 + nt*16 + lr)*136 + ks*32 + lq*8];
      acc[0][nt] = __builtin_amdgcn_mfma_f32_16x16x32_bf16(a0, bb, acc[0][nt], 0, 0, 0);
      acc[1][nt] = __builtin_amdgcn_mfma_f32_16x16x32_bf16(a1, bb, acc[1][nt], 0, 0, 0);
    }
  }
  __syncthreads();
  float* ct = (float*)smr;  // [64][132] f32
#pragma unroll
  for (int mt = 0; mt < 2; ++mt)
#pragma unroll
    for (int nt = 0; nt < 4; ++nt)
#pragma unroll
      for (int r = 0; r < 4; ++r){
        int row = wm*32 + mt*16 + lq*4 + r;
        ct[row*132 + wn*64 + nt*16 + lr] = acc[mt][nt][r] + biasf[c0 + row];
      }
  __syncthreads();
  if (*flag){
    float* of = (float*)outv;
#pragma unroll
    for (int i = 0; i < 8; ++i){ int ch = i*256 + t; int r = ch>>5, c4 = (ch&31)*4;
      *(float4*)&of[((size_t)(b*512 + c0 + r))*4096 + n0 + c4] = *(float4*)&ct[r*132 + c4]; }
  } else {
    unsigned short* ob = (unsigned short*)outv;
#pragma unroll
    for (int i = 0; i < 4; ++i){ int ch = i*256 + t; int r = ch>>4, c8 = (ch&15)*8;
      unsigned short tmp[8] __attribute__((aligned(16)));
#pragma unroll
      for (int j = 0; j < 8; ++j) tmp[j] = f2bf(ct[r*132 + c8 + j]);
      *(short8_t*)&ob[((size_t)(b*512 + c0 + r))*4096 + n0 + c8] = *(short8_t*)tmp; }
  }
}

extern "C" void kernel_launch(void* const* d_in, const int* in_sizes, int n_in,
                              void* d_out, int out_size, void* d_ws, size_t ws_size,
                              hipStream_t stream){
  (void)in_sizes; (void)n_in; (void)out_size; (void)ws_size;
  char* ws = (char*)d_ws;
  int* flag              = (int*)ws;
  unsigned short* xT     = (unsigned short*)(ws + OFF_XT);
  unsigned short* Pg     = (unsigned short*)(ws + OFF_KVX);              // [8][4096][128] bf16 = 8 MB
  unsigned short* Mg     = (unsigned short*)(ws + OFF_KVX + 8388608ull); // [8][512][128] bf16
  unsigned short* wkvx   = (unsigned short*)(ws + OFF_WKVX);
  unsigned short* wqx    = (unsigned short*)(ws + OFF_WQX);
  unsigned short* wkvl   = (unsigned short*)(ws + OFF_WKVL);
  unsigned short* wproj  = (unsigned short*)(ws + OFF_WPROJ);
  float* latf  = (float*)(ws + OFF_LATF);
  float* biasf = (float*)(ws + OFF_BIAS);
  float* qlh   = (float*)(ws + OFF_QLH);
  float* gnum  = (float*)(ws + OFF_GNUM);
  float* gden  = (float*)(ws + OFF_GDEN);
  float* kvl   = (float*)(ws + OFF_KVL);
  float* khat  = (float*)(ws + OFF_KHAT);
  float* gvl   = (float*)(ws + OFF_GVL);

  k_sniff<<<1, 256, 0, stream>>>((const unsigned short*)d_in[0], flag);

  // weights (contiguous dst), latents, bias in one launch
  k_prep<<<901, 256, 0, stream>>>(d_in[3], d_in[4], d_in[5], d_in[6], d_in[2],
                                  d_in[1], d_in[7], wkvx, latf, biasf, flag);

  k_xt<<<dim3(64, 8, 8), 256, 0, stream>>>(d_in[0], xT, flag);

  k_ql<<<8, 256, 8192 + 17408 + 4096 + 64, stream>>>((unsigned short*)(ws + OFF_WQLAT), latf, qlh);

  hipMemsetAsync(ws + OFF_GNUM, 0, 524288 + 4096, stream);       // gnum + gden

  k_kvattn1<<<dim3(32, 8, 8), 256, 43264, stream>>>(wkvx, xT, qlh, gnum, gden);
  k_kvl<<<dim3(64, 8), 256, 32768 + 16*136*2, stream>>>(wkvl, gnum, gden, kvl);
  k_klnorm<<<dim3(16, 8, 8), 64, 0, stream>>>(kvl, khat, gvl);
  k_mmat<<<dim3(4, 8, 8), 256, 0, stream>>>(wproj, gvl, Mg);
  k_attn2p2<<<dim3(32, 4, 8), 256, 42496, stream>>>(wqx, xT, khat, Pg);
  k_out<<<dim3(32, 8, 8), 256, 52224, stream>>>(Mg, Pg, biasf, d_out, flag);
}

// Round 5
// 301.263 us; speedup vs baseline: 1.3532x; 1.0307x over previous
//
#include <hip/hip_runtime.h>

// LatentMixer on MI355X. bf16-MFMA pipeline with runtime input-dtype sniffing.
// B=8, C=512, HW=4096, L=16, heads=8, d=64, scale=0.125, eps=1e-12.
// R2: out = (w_proj@blockdiag(V)) @ P + bias (algebraic fusion).
// R3: attn1 fused into kv-GEMM epilogue; 128x128 tiles.
// R4: global_load_lds width=16 staging.
// R5: XOR-swizzled glld layout (R4 regressed: unpadded 128B rows -> 16-way bank conflicts).

typedef __bf16 bf16x8 __attribute__((ext_vector_type(8)));
typedef float floatx4 __attribute__((ext_vector_type(4)));
typedef short short8_t __attribute__((ext_vector_type(8)));
typedef short short4_t __attribute__((ext_vector_type(4)));

#define DEV __device__ __forceinline__

DEV float bf2f(unsigned short u){ union{unsigned int i; float f;} v; v.i = ((unsigned int)u)<<16; return v.f; }
DEV unsigned short f2bf(float f){
  union{float f; unsigned int i;} v; v.f = f;
  unsigned int i = v.i;
  return (unsigned short)((i + 0x7fffu + ((i>>16)&1u)) >> 16);
}

// async global->LDS, 16 B per lane; LDS dest = base + lane*16 (wave-uniform base!)
DEV void glds16(const void* g, void* l){
  __builtin_amdgcn_global_load_lds((const __attribute__((address_space(1))) void*)g,
                                   (__attribute__((address_space(3))) void*)l, 16, 0, 0);
}

// ---------------- workspace layout (bytes) ----------------
#define OFF_XT     256ull                          // xT bf16 [8][4096][512]
#define OFF_KVX    (OFF_XT + 33554432ull)          // region reused: Pg bf16 [8][4096][128] + Mg
#define OFF_WKVX   (OFF_KVX + 67108864ull)         // w_kv_x bf16   (weights contiguous from here)
#define OFF_WQX    (OFF_WKVX + 1048576ull)         // w_q_x bf16
#define OFF_WKVL   (OFF_WQX + 524288ull)           // w_kv_lat bf16
#define OFF_WPROJ  (OFF_WKVL + 1048576ull)         // w_proj bf16
#define OFF_WQLAT  (OFF_WPROJ + 524288ull)         // w_q_lat bf16
#define OFF_LATF   (OFF_WQLAT + 524288ull)         // latents f32 [512][16]
#define OFF_BIAS   (OFF_LATF + 32768ull)           // bias f32 [512]
#define OFF_QLH    (OFF_BIAS + 4096ull)            // ql-hat f32 [h][l][64] (0.125 folded)
#define OFF_GNUM   (OFF_QLH + 32768ull)            // attn1 numerator f32 [b][h][l][64]
#define OFF_GDEN   (OFF_GNUM + 524288ull)          // attn1 denominator f32 [b][h][l]
#define OFF_KVL    (OFF_GDEN + 4096ull)            // kvl f32 [b][1024][16]
#define OFF_KHAT   (OFF_KVL + 524288ull)           // k-hat f32 [b][h][l][64] (0.125 folded)
#define OFF_GVL    (OFF_KHAT + 524288ull)          // vl f32 [b][h][l][64]

// ---------------- dtype sniff ----------------
__global__ void k_sniff(const unsigned short* __restrict__ x, int* flag){
  int t = threadIdx.x;
  int m = 0;
  for (int i = t; i < 4096; i += 256){ int e = (x[i]>>7)&0xFF; m = (e>m)?e:m; }
  __shared__ int red[256];
  red[t] = m; __syncthreads();
  for (int s = 128; s > 0; s >>= 1){ if (t < s) red[t] = (red[t+s]>red[t])?red[t+s]:red[t]; __syncthreads(); }
  if (t == 0) flag[0] = (red[0] > 150) ? 1 : 0;   // 1 => fp32 inputs, 0 => bf16 inputs
}

// ---------------- fused prep: all 5 weight converts + latents + bias ----------------
__global__ __launch_bounds__(256) void k_prep(const void* s0, const void* s1, const void* s2,
                                              const void* s3, const void* s4,
                                              const void* slat, const void* sbias,
                                              unsigned short* __restrict__ wdst,
                                              float* __restrict__ latf, float* __restrict__ biasf,
                                              const int* __restrict__ flag){
  int b = blockIdx.x, t = threadIdx.x;
  int isf = *flag;
  if (b < 896){
    int e = b*2048 + t*8;
    const void* src; int off;
    if (e < 524288)      { src = s0; off = e; }
    else if (e < 786432) { src = s1; off = e - 524288; }
    else if (e < 1310720){ src = s2; off = e - 786432; }
    else if (e < 1572864){ src = s3; off = e - 1310720; }
    else                 { src = s4; off = e - 1572864; }
    if (isf){
      const float* s = (const float*)src + off;
      float4 v0 = *(const float4*)(s);
      float4 v1 = *(const float4*)(s+4);
      unsigned short tmp[8] __attribute__((aligned(16)));
      tmp[0]=f2bf(v0.x); tmp[1]=f2bf(v0.y); tmp[2]=f2bf(v0.z); tmp[3]=f2bf(v0.w);
      tmp[4]=f2bf(v1.x); tmp[5]=f2bf(v1.y); tmp[6]=f2bf(v1.z); tmp[7]=f2bf(v1.w);
      *(short8_t*)&wdst[e] = *(short8_t*)tmp;
    } else {
      *(short8_t*)&wdst[e] = *(const short8_t*)((const unsigned short*)src + off);
    }
  } else if (b < 900){
    int i = (b-896)*2048 + t*8;
#pragma unroll
    for (int j = 0; j < 8; ++j)
      latf[i+j] = isf ? ((const float*)slat)[i+j] : bf2f(((const unsigned short*)slat)[i+j]);
  } else {
    if (t < 512) biasf[t] = isf ? ((const float*)sbias)[t] : bf2f(((const unsigned short*)sbias)[t]);
  }
}

// ---------------- transpose x[b][c][n] -> xT[b][n][c] (bf16) ----------------
__global__ __launch_bounds__(256) void k_xt(const void* __restrict__ xraw, unsigned short* __restrict__ xT,
                                            const int* __restrict__ flag){
  int nb = blockIdx.x, cb = blockIdx.y, b = blockIdx.z;
  int n0 = nb*64, c0 = cb*64;
  __shared__ unsigned short tile[64][72];   // XOR-swizzled columns: col = n ^ (((row>>3)&7)<<3)
  int t = threadIdx.x;
  if (*flag){
    const float* xp = (const float*)xraw;
#pragma unroll
    for (int i = 0; i < 4; ++i){
      int ch = i*256 + t; int c = ch>>4, n4 = (ch&15)*4;
      float4 v = *(const float4*)&xp[((size_t)(b*512 + c0 + c))*4096 + n0 + n4];
      int cc = n4 ^ (((c>>3)&7)<<3);
      tile[c][cc+0]=f2bf(v.x); tile[c][cc+1]=f2bf(v.y); tile[c][cc+2]=f2bf(v.z); tile[c][cc+3]=f2bf(v.w);
    }
  } else {
    const unsigned short* xp = (const unsigned short*)xraw;
#pragma unroll
    for (int i = 0; i < 2; ++i){
      int ch = i*256 + t; int c = ch>>3, n8 = (ch&7)*8;
      *(short8_t*)&tile[c][n8 ^ (((c>>3)&7)<<3)] =
        *(const short8_t*)&xp[((size_t)(b*512 + c0 + c))*4096 + n0 + n8];
    }
  }
  __syncthreads();
#pragma unroll
  for (int i = 0; i < 2; ++i){
    int ch = i*256 + t; int n = ch>>3, c8 = (ch&7)*8;
    unsigned short tmp[8] __attribute__((aligned(16)));
#pragma unroll
    for (int j = 0; j < 8; ++j){
      int c = c8 + j;
      tmp[j] = tile[c][n ^ (((c>>3)&7)<<3)];
    }
    *(short8_t*)&xT[((size_t)(b*4096 + n0 + n))*512 + c0 + c8] = *(short8_t*)tmp;
  }
}

// ---------------- ql = w_q_lat @ latents + normalize -> qlhat [h][l][64], 0.125 folded ----------------
__global__ __launch_bounds__(256) void k_ql(const unsigned short* __restrict__ wqlat,
                                            const float* __restrict__ latf, float* __restrict__ qlh){
  int h = blockIdx.x, o0 = h*64;
  extern __shared__ char smr[];
  float* latb = (float*)smr;                          // [128][16] = 8192
  unsigned short* wt = (unsigned short*)(smr + 8192); // [64][136] = 17408
  float* qbuf = (float*)(smr + 8192 + 17408);         // [64][16] = 4096
  float* rinv = (float*)(smr + 8192 + 17408 + 4096);  // [16]
  int t = threadIdx.x;
  int o = t>>2, l4 = (t&3)*4;
  float acc[4] = {0.f,0.f,0.f,0.f};
  for (int kk = 0; kk < 512; kk += 128){
    __syncthreads();
#pragma unroll
    for (int j = 0; j < 8; ++j){ int i = j*256 + t; latb[i] = latf[kk*16 + i]; }
#pragma unroll
    for (int j = 0; j < 4; ++j){ int ch = j*256 + t; int r = ch>>4, kc = (ch&15)*8;
      *(short8_t*)&wt[r*136 + kc] = *(const short8_t*)&wqlat[(size_t)(o0+r)*512 + kk + kc]; }
    __syncthreads();
    for (int k = 0; k < 128; ++k){
      float w = bf2f(wt[o*136 + k]);
      const float* lr = &latb[k*16 + l4];
#pragma unroll
      for (int j = 0; j < 4; ++j) acc[j] += w*lr[j];
    }
  }
#pragma unroll
  for (int j = 0; j < 4; ++j) qbuf[o*16 + l4 + j] = acc[j];
  __syncthreads();
  if (t < 16){
    float ss = 0.f;
    for (int oo = 0; oo < 64; ++oo){ float v = qbuf[oo*16 + t]; ss += v*v; }
    rinv[t] = 0.125f / fmaxf(sqrtf(ss), 1e-12f);
  }
  __syncthreads();
#pragma unroll
  for (int j = 0; j < 4; ++j) qlh[(h*16 + l4 + j)*64 + o] = acc[j]*rinv[l4 + j];
}

// ---------------- 128x128 MFMA GEMM core, K=512, swizzled global_load_lds staging ----------------
// LDS: At [128][64] shorts at smr, Bt at smr+16384 (UNPADDED, XOR-swizzled k8 within row:
// LDS slot (r, k8) holds global (r, k8 ^ (r&7))). Write: lane (rsub=lane>>3,k8=lane&7) fetches
// global k8^rsub. Read: addr = r*64 + ((ks*4+lq)^(lr&7))*8 -> uniform 8-lanes-per-16B-position.
DEV void gemm128(const unsigned short* __restrict__ Ap0, const unsigned short* __restrict__ Ap1,
                 const unsigned short* __restrict__ Bp,
                 unsigned short* At, unsigned short* Bt, floatx4 (&acc)[4][4]){
  int t = threadIdx.x, lane = t&63, wave = t>>6;
  int wm = wave>>1, wn = wave&1, lr = lane&15, lq = lane>>4;
  int rsub = lane>>3;                 // 0..7: row within 8-row chunk
  int koff = ((lane&7) ^ rsub)*8;     // swizzled global k8 slot (shorts)
  int sw = lr&7;                      // read-side XOR factor
  for (int kk = 0; kk < 512; kk += 64){
    __syncthreads();
#pragma unroll
    for (int c2 = 0; c2 < 4; ++c2){
      int chunk = wave*4 + c2;           // 0..15, wave-uniform
      int row = chunk*8 + rsub;
      const unsigned short* gp = (chunk < 8) ? (Ap0 + (size_t)row*512 + kk + koff)
                                             : (Ap1 + (size_t)(row-64)*512 + kk + koff);
      glds16(gp, At + chunk*512);
    }
#pragma unroll
    for (int c2 = 0; c2 < 4; ++c2){
      int chunk = wave*4 + c2;
      int row = chunk*8 + rsub;
      glds16(Bp + (size_t)row*512 + kk + koff, Bt + chunk*512);
    }
    __syncthreads();   // drains vmcnt (glld) before LDS reads
#pragma unroll
    for (int ks = 0; ks < 2; ++ks){
      int vo = ((ks*4 + lq) ^ sw)*8;
      bf16x8 a[4], b[4];
#pragma unroll
      for (int mt = 0; mt < 4; ++mt) a[mt] = *(const bf16x8*)&At[(wm*64 + mt*16 + lr)*64 + vo];
#pragma unroll
      for (int nt = 0; nt < 4; ++nt) b[nt] = *(const bf16x8*)&Bt[(wn*64 + nt*16 + lr)*64 + vo];
#pragma unroll
      for (int mt = 0; mt < 4; ++mt)
#pragma unroll
        for (int nt = 0; nt < 4; ++nt)
          acc[mt][nt] = __builtin_amdgcn_mfma_f32_16x16x32_bf16(a[mt], b[nt], acc[mt][nt], 0, 0, 0);
    }
  }
  __syncthreads();  // protects LDS reuse by epilogues
}

// ---------------- fused kv-GEMM + attn1: M-tile = [k_h(64); v_h(64)], N=128 positions ----------------
// LDS: staging 0..32768. Epilogue: kt [128][72] @0 (18432), vt [64][136] @18432 (->35840),
// qls [16][72] @35840 (->38144), ssq @38144 (->38656), wred @38656 (->38912),
// pt [16][136] @38912 (->43264). Total 43264.
__global__ __launch_bounds__(256) void k_kvattn1(const unsigned short* __restrict__ wkvx,
                                                 const unsigned short* __restrict__ xT,
                                                 const float* __restrict__ qlh2,
                                                 float* __restrict__ gnum, float* __restrict__ gden){
  int nb = blockIdx.x, h = blockIdx.y, b = blockIdx.z;
  int n0 = nb*128;
  extern __shared__ char smr[];
  unsigned short* At  = (unsigned short*)smr;
  unsigned short* Bt  = (unsigned short*)(smr + 16384);
  unsigned short* kt  = (unsigned short*)smr;            // [128 n][72] k-hat, d contiguous
  unsigned short* vt  = (unsigned short*)(smr + 18432);  // [64 d][136]
  unsigned short* qls = (unsigned short*)(smr + 35840);  // [16 l][72] 0.125*q-hat
  float* ssq  = (float*)(smr + 38144);                   // [128] rinv
  float* wred = (float*)(smr + 38656);                   // [4][16]
  unsigned short* pt  = (unsigned short*)(smr + 38912);  // [16 l][136] p bf16
  int t = threadIdx.x, lane = t&63, wave = t>>6;
  int wm = wave>>1, wn = wave&1, lr = lane&15, lq = lane>>4;
  // stage 0.125*q-hat [16][72] (outside staging region; before GEMM to overlap)
  for (int i = t; i < 1024; i += 256) qls[(i>>6)*72 + (i&63)] = f2bf(qlh2[(size_t)h*1024 + i]);
  floatx4 acc[4][4];
  floatx4 zero = {0.f,0.f,0.f,0.f};
#pragma unroll
  for (int i = 0; i < 4; ++i) for (int j = 0; j < 4; ++j) acc[i][j] = zero;
  gemm128(wkvx + (size_t)(h*64)*512, wkvx + (size_t)(512 + h*64)*512,
          xT + ((size_t)(b*4096 + n0))*512, At, Bt, acc);
  if (wm == 0){
    // k column inverse norms from f32 accumulators
#pragma unroll
    for (int nt = 0; nt < 4; ++nt){
      float s = 0.f;
#pragma unroll
      for (int mt = 0; mt < 4; ++mt)
#pragma unroll
        for (int r = 0; r < 4; ++r) s += acc[mt][nt][r]*acc[mt][nt][r];
      s += __shfl_xor(s, 16); s += __shfl_xor(s, 32);
      if (lq == 0) ssq[wn*64 + nt*16 + lr] = 1.f / fmaxf(sqrtf(s), 1e-12f);
    }
  } else {
    // v tile to LDS [d][n]
#pragma unroll
    for (int mt = 0; mt < 4; ++mt)
#pragma unroll
      for (int nt = 0; nt < 4; ++nt){
        int col = wn*64 + nt*16 + lr;
#pragma unroll
        for (int r = 0; r < 4; ++r) vt[(mt*16 + lq*4 + r)*136 + col] = f2bf(acc[mt][nt][r]);
      }
  }
  __syncthreads();
  if (wm == 0){
    // k-hat tile to LDS transposed [n][d], norm folded
#pragma unroll
    for (int nt = 0; nt < 4; ++nt){
      int col = wn*64 + nt*16 + lr;
      float rinv = ssq[col];
#pragma unroll
      for (int mt = 0; mt < 4; ++mt){
        unsigned short tmp[4] __attribute__((aligned(8)));
#pragma unroll
        for (int r = 0; r < 4; ++r) tmp[r] = f2bf(acc[mt][nt][r]*rinv);
        *(short4_t*)&kt[col*72 + mt*16 + lq*4] = *(short4_t*)tmp;
      }
    }
  }
  __syncthreads();
  // S^T[n][l] via MFMA: A = kt rows n, B = qls rows l, K=64
  floatx4 sl[2]; sl[0] = zero; sl[1] = zero;
#pragma unroll
  for (int ks = 0; ks < 2; ++ks){
    bf16x8 bb = *(const bf16x8*)&qls[lr*72 + ks*32 + lq*8];
#pragma unroll
    for (int i = 0; i < 2; ++i){
      bf16x8 aa = *(const bf16x8*)&kt[((wave*2 + i)*16 + lr)*72 + ks*32 + lq*8];
      sl[i] = __builtin_amdgcn_mfma_f32_16x16x32_bf16(aa, bb, sl[i], 0, 0, 0);
    }
  }
  // p = exp(s) (|s| <= 0.125); den partials; p to LDS [l][n]
  float dp = 0.f;
  float pv[2][4];
#pragma unroll
  for (int i = 0; i < 2; ++i)
#pragma unroll
    for (int r = 0; r < 4; ++r){ float p = __expf(sl[i][r]); pv[i][r] = p; dp += p; }
  dp += __shfl_xor(dp, 16); dp += __shfl_xor(dp, 32);
  if (lq == 0) wred[wave*16 + lr] = dp;
#pragma unroll
  for (int i = 0; i < 2; ++i){
    unsigned short tmp[4] __attribute__((aligned(8)));
#pragma unroll
    for (int r = 0; r < 4; ++r) tmp[r] = f2bf(pv[i][r]);
    *(short4_t*)&pt[lr*136 + (wave*2 + i)*16 + lq*4] = *(short4_t*)tmp;
  }
  __syncthreads();
  int bh = b*8 + h;
  if (t < 16) atomicAdd(&gden[bh*16 + t], wred[t] + wred[16+t] + wred[32+t] + wred[48+t]);
  // num^T[d][l] via MFMA: A = vt rows d (wave*16 block), B = pt rows l, K=128
  floatx4 nacc = zero;
#pragma unroll
  for (int ks = 0; ks < 4; ++ks){
    bf16x8 aa = *(const bf16x8*)&vt[(wave*16 + lr)*136 + ks*32 + lq*8];
    bf16x8 bb = *(const bf16x8*)&pt[lr*136 + ks*32 + lq*8];
    nacc = __builtin_amdgcn_mfma_f32_16x16x32_bf16(aa, bb, nacc, 0, 0, 0);
  }
  float* gp = &gnum[((size_t)bh*16 + lr)*64 + wave*16 + lq*4];
#pragma unroll
  for (int r = 0; r < 4; ++r) atomicAdd(&gp[r], nacc[r]);
}

// ---------------- kvl = w_kv_lat @ (num/den), f32 [b][o][l] ----------------
__global__ __launch_bounds__(256) void k_kvl(const unsigned short* __restrict__ wkvl,
                                             const float* __restrict__ gnum, const float* __restrict__ gden,
                                             float* __restrict__ kvl){
  int ob = blockIdx.x, b = blockIdx.y;
  extern __shared__ char smr[];
  float* latb = (float*)smr;                         // [512][16]
  unsigned short* wt = (unsigned short*)(smr + 32768); // [16][136]
  int t = threadIdx.x;
  for (int i = t; i < 8192; i += 256){
    int c = i>>4, l = i&15;
    int h = c>>6, d = c&63;
    int bh = b*8 + h;
    latb[i] = gnum[((size_t)(bh*16 + l))*64 + d] / gden[bh*16 + l];
  }
  int o = t>>4, l = t&15;
  int o0 = ob*16;
  float acc = 0.f;
  for (int kk = 0; kk < 512; kk += 128){
    __syncthreads();
    { int r = t>>4, kc = (t&15)*8;
      *(short8_t*)&wt[r*136 + kc] = *(const short8_t*)&wkvl[(size_t)(o0+r)*512 + kk + kc]; }
    __syncthreads();
    for (int k = 0; k < 128; ++k) acc += bf2f(wt[o*136 + k]) * latb[(kk+k)*16 + l];
  }
  kvl[((size_t)(b*1024 + o0 + o))*16 + l] = acc;
}

// normalize kl per (b,h,l); khat gets 0.125 folded; gvl raw
__global__ void k_klnorm(const float* __restrict__ kvl, float* __restrict__ khat, float* __restrict__ gvl){
  int l = blockIdx.x, h = blockIdx.y, b = blockIdx.z, d = threadIdx.x;
  float kl = kvl[((size_t)(b*1024 + h*64 + d))*16 + l];
  float vl = kvl[((size_t)(b*1024 + 512 + h*64 + d))*16 + l];
  float ss = kl*kl;
  for (int off = 32; off; off >>= 1) ss += __shfl_xor(ss, off);
  float inv = 0.125f / fmaxf(sqrtf(ss), 1e-12f);
  size_t o = ((size_t)((b*8+h)*16 + l))*64 + d;
  khat[o] = kl*inv;
  gvl[o] = vl;
}

// ---------------- Mmat: M[b][c][h*16+l] = sum_d wproj[c][h*64+d] * vl[b][h][l][d] ----------------
__global__ __launch_bounds__(256) void k_mmat(const unsigned short* __restrict__ wproj,
                                              const float* __restrict__ gvl,
                                              unsigned short* __restrict__ Mg){
  int cb = blockIdx.x, h = blockIdx.y, b = blockIdx.z;
  __shared__ unsigned short wt[128*68];
  int t = threadIdx.x;
#pragma unroll
  for (int i = 0; i < 4; ++i){ int ch = i*256 + t; int c = ch>>3, d8 = (ch&7)*8;
    *(short8_t*)&wt[c*68 + d8] = *(const short8_t*)&wproj[(size_t)(cb*128 + c)*512 + h*64 + d8]; }
  int l = t&15, cq = t>>4;
  float v[64];
  const float* vp = &gvl[((size_t)(b*8+h)*16 + l)*64];
#pragma unroll
  for (int j = 0; j < 16; ++j){ float4 f = *(const float4*)&vp[j*4];
    v[j*4+0]=f.x; v[j*4+1]=f.y; v[j*4+2]=f.z; v[j*4+3]=f.w; }
  __syncthreads();
#pragma unroll
  for (int c8 = 0; c8 < 8; ++c8){
    int c = cq*8 + c8;
    float dot = 0.f;
#pragma unroll
    for (int d = 0; d < 64; ++d) dot += bf2f(wt[c*68 + d]) * v[d];
    Mg[((size_t)(b*512) + cb*128 + c)*128 + h*16 + l] = f2bf(dot);
  }
}

// ---------------- attn2 probs: 128x128 q-GEMM (2 heads) + MFMA dots + softmax -> P bf16 ----------------
// LDS: staging 0..32768. Epilogue: qt0 [128][72] @0, qt1 @18432 (->36864),
// khs [2][16][72] @36864 (->41472), ssq [2][128] @41472 (->42496). Total 42496.
__global__ __launch_bounds__(256) void k_attn2p2(const unsigned short* __restrict__ wqx,
                                                 const unsigned short* __restrict__ xT,
                                                 const float* __restrict__ khatg,
                                                 unsigned short* __restrict__ Pg){
  int nb = blockIdx.x, hp = blockIdx.y, b = blockIdx.z;
  int n0 = nb*128;
  extern __shared__ char smr[];
  unsigned short* At  = (unsigned short*)smr;
  unsigned short* Bt  = (unsigned short*)(smr + 16384);
  unsigned short* qt0 = (unsigned short*)smr;            // head hp*2   q-hat [128 n][72]
  unsigned short* qt1 = (unsigned short*)(smr + 18432);  // head hp*2+1
  unsigned short* khs = (unsigned short*)(smr + 36864);  // [2][16][72]
  float* ssq = (float*)(smr + 41472);                    // [2][128] rinv
  int t = threadIdx.x, lane = t&63, wave = t>>6;
  int wm = wave>>1, wn = wave&1, lr = lane&15, lq = lane>>4;
  // stage k-hat (0.125 folded) for both heads (outside staging region)
  for (int i = t; i < 2048; i += 256){
    int hh = i>>10, rem = i&1023;
    khs[hh*1152 + (rem>>6)*72 + (rem&63)] = f2bf(khatg[((size_t)(b*8 + hp*2 + hh))*1024 + rem]);
  }
  floatx4 acc[4][4];
  floatx4 zero = {0.f,0.f,0.f,0.f};
#pragma unroll
  for (int i = 0; i < 4; ++i) for (int j = 0; j < 4; ++j) acc[i][j] = zero;
  gemm128(wqx + (size_t)(hp*128)*512, wqx + (size_t)(hp*128 + 64)*512,
          xT + ((size_t)(b*4096 + n0))*512, At, Bt, acc);
  // per-head column inverse norms (wave wm covers head wm's 64 rows)
#pragma unroll
  for (int nt = 0; nt < 4; ++nt){
    float s = 0.f;
#pragma unroll
    for (int mt = 0; mt < 4; ++mt)
#pragma unroll
      for (int r = 0; r < 4; ++r) s += acc[mt][nt][r]*acc[mt][nt][r];
    s += __shfl_xor(s, 16); s += __shfl_xor(s, 32);
    if (lq == 0) ssq[wm*128 + wn*64 + nt*16 + lr] = 1.f / fmaxf(sqrtf(s), 1e-12f);
  }
  __syncthreads();
  // q-hat tiles to LDS transposed [n][d], norm folded
  unsigned short* qtr = wm ? qt1 : qt0;
#pragma unroll
  for (int nt = 0; nt < 4; ++nt){
    int col = wn*64 + nt*16 + lr;
    float rinv = ssq[wm*128 + col];
#pragma unroll
    for (int mt = 0; mt < 4; ++mt){
      unsigned short tmp[4] __attribute__((aligned(8)));
#pragma unroll
      for (int r = 0; r < 4; ++r) tmp[r] = f2bf(acc[mt][nt][r]*rinv);
      *(short4_t*)&qtr[col*72 + mt*16 + lq*4] = *(short4_t*)tmp;
    }
  }
  __syncthreads();
  // S^T[n][l]: wave handles head wm, n-half wn (4 m-tiles), K=64
  floatx4 sl[4];
#pragma unroll
  for (int i = 0; i < 4; ++i) sl[i] = zero;
  unsigned short* qsrc = wm ? qt1 : qt0;
#pragma unroll
  for (int ks = 0; ks < 2; ++ks){
    bf16x8 bb = *(const bf16x8*)&khs[wm*1152 + lr*72 + ks*32 + lq*8];
#pragma unroll
    for (int i = 0; i < 4; ++i){
      bf16x8 aa = *(const bf16x8*)&qsrc[((wn*4 + i)*16 + lr)*72 + ks*32 + lq*8];
      sl[i] = __builtin_amdgcn_mfma_f32_16x16x32_bf16(aa, bb, sl[i], 0, 0, 0);
    }
  }
  int h = hp*2 + wm;
#pragma unroll
  for (int i = 0; i < 4; ++i){
    float p[4], s[4];
#pragma unroll
    for (int r = 0; r < 4; ++r){ p[r] = __expf(sl[i][r]); s[r] = p[r]; }
#pragma unroll
    for (int r = 0; r < 4; ++r){
      s[r] += __shfl_xor(s[r], 1);
      s[r] += __shfl_xor(s[r], 2);
      s[r] += __shfl_xor(s[r], 4);
      s[r] += __shfl_xor(s[r], 8);
    }
    int nbase = wn*64 + i*16 + lq*4;
#pragma unroll
    for (int r = 0; r < 4; ++r)
      Pg[((size_t)(b*4096 + n0 + nbase + r))*128 + h*16 + lr] = f2bf(p[r]/s[r]);
  }
}

// ---------------- out = M @ P + bias: 64x128 tile, K=128 ----------------
__global__ __launch_bounds__(256) void k_out(const unsigned short* __restrict__ Mg,
                                             const unsigned short* __restrict__ Pg,
                                             const float* __restrict__ biasf,
                                             void* __restrict__ outv, const int* __restrict__ flag){
  int nb = blockIdx.x, cb = blockIdx.y, b = blockIdx.z;
  int n0 = nb*128, c0 = cb*64;
  extern __shared__ char smr[];
  unsigned short* At = (unsigned short*)smr;   // [64][136]
  unsigned short* Bt = At + 64*136;            // [128][136]
  int t = threadIdx.x, lane = t&63, wave = t>>6;
  int wm = wave>>1, wn = wave&1, lr = lane&15, lq = lane>>4;
#pragma unroll
  for (int i = 0; i < 4; ++i){ int ch = i*256 + t; int r = ch>>4, p8 = (ch&15)*8;
    *(short8_t*)&At[r*136 + p8] = *(const short8_t*)&Mg[((size_t)(b*512 + c0 + r))*128 + p8]; }
#pragma unroll
  for (int i = 0; i < 8; ++i){ int ch = i*256 + t; int r = ch>>4, p8 = (ch&15)*8;
    *(short8_t*)&Bt[r*136 + p8] = *(const short8_t*)&Pg[((size_t)(b*4096 + n0 + r))*128 + p8]; }
  __syncthreads();
  floatx4 acc[2][4];
  floatx4 zero = {0.f,0.f,0.f,0.f};
#pragma unroll
  for (int i = 0; i < 2; ++i) for (int j = 0; j < 4; ++j) acc[i][j] = zero;
#pragma unroll
  for (int ks = 0; ks < 4; ++ks){
    bf16x8 a0 = *(const bf16x8*)&At[(wm*32 + lr)*136 + ks*32 + lq*8];
    bf16x8 a1 = *(const bf16x8*)&At[(wm*32 + 16 + lr)*136 + ks*32 + lq*8];
#pragma unroll
    for (int nt = 0; nt < 4; ++nt){
      bf16x8 bb = *(const bf16x8*)&Bt[(wn*64 + nt*16 + lr)*136 + ks*32 + lq*8];
      acc[0][nt] = __builtin_amdgcn_mfma_f32_16x16x32_bf16(a0, bb, acc[0][nt], 0, 0, 0);
      acc[1][nt] = __builtin_amdgcn_mfma_f32_16x16x32_bf16(a1, bb, acc[1][nt], 0, 0, 0);
    }
  }
  __syncthreads();
  float* ct = (float*)smr;  // [64][132] f32
#pragma unroll
  for (int mt = 0; mt < 2; ++mt)
#pragma unroll
    for (int nt = 0; nt < 4; ++nt)
#pragma unroll
      for (int r = 0; r < 4; ++r){
        int row = wm*32 + mt*16 + lq*4 + r;
        ct[row*132 + wn*64 + nt*16 + lr] = acc[mt][nt][r] + biasf[c0 + row];
      }
  __syncthreads();
  if (*flag){
    float* of = (float*)outv;
#pragma unroll
    for (int i = 0; i < 8; ++i){ int ch = i*256 + t; int r = ch>>5, c4 = (ch&31)*4;
      *(float4*)&of[((size_t)(b*512 + c0 + r))*4096 + n0 + c4] = *(float4*)&ct[r*132 + c4]; }
  } else {
    unsigned short* ob = (unsigned short*)outv;
#pragma unroll
    for (int i = 0; i < 4; ++i){ int ch = i*256 + t; int r = ch>>4, c8 = (ch&15)*8;
      unsigned short tmp[8] __attribute__((aligned(16)));
#pragma unroll
      for (int j = 0; j < 8; ++j) tmp[j] = f2bf(ct[r*132 + c8 + j]);
      *(short8_t*)&ob[((size_t)(b*512 + c0 + r))*4096 + n0 + c8] = *(short8_t*)tmp; }
  }
}

extern "C" void kernel_launch(void* const* d_in, const int* in_sizes, int n_in,
                              void* d_out, int out_size, void* d_ws, size_t ws_size,
                              hipStream_t stream){
  (void)in_sizes; (void)n_in; (void)out_size; (void)ws_size;
  char* ws = (char*)d_ws;
  int* flag              = (int*)ws;
  unsigned short* xT     = (unsigned short*)(ws + OFF_XT);
  unsigned short* Pg     = (unsigned short*)(ws + OFF_KVX);              // [8][4096][128] bf16 = 8 MB
  unsigned short* Mg     = (unsigned short*)(ws + OFF_KVX + 8388608ull); // [8][512][128] bf16
  unsigned short* wkvx   = (unsigned short*)(ws + OFF_WKVX);
  unsigned short* wqx    = (unsigned short*)(ws + OFF_WQX);
  unsigned short* wkvl   = (unsigned short*)(ws + OFF_WKVL);
  unsigned short* wproj  = (unsigned short*)(ws + OFF_WPROJ);
  float* latf  = (float*)(ws + OFF_LATF);
  float* biasf = (float*)(ws + OFF_BIAS);
  float* qlh   = (float*)(ws + OFF_QLH);
  float* gnum  = (float*)(ws + OFF_GNUM);
  float* gden  = (float*)(ws + OFF_GDEN);
  float* kvl   = (float*)(ws + OFF_KVL);
  float* khat  = (float*)(ws + OFF_KHAT);
  float* gvl   = (float*)(ws + OFF_GVL);

  k_sniff<<<1, 256, 0, stream>>>((const unsigned short*)d_in[0], flag);

  // weights (contiguous dst), latents, bias in one launch
  k_prep<<<901, 256, 0, stream>>>(d_in[3], d_in[4], d_in[5], d_in[6], d_in[2],
                                  d_in[1], d_in[7], wkvx, latf, biasf, flag);

  k_xt<<<dim3(64, 8, 8), 256, 0, stream>>>(d_in[0], xT, flag);

  k_ql<<<8, 256, 8192 + 17408 + 4096 + 64, stream>>>((unsigned short*)(ws + OFF_WQLAT), latf, qlh);

  hipMemsetAsync(ws + OFF_GNUM, 0, 524288 + 4096, stream);       // gnum + gden

  k_kvattn1<<<dim3(32, 8, 8), 256, 43264, stream>>>(wkvx, xT, qlh, gnum, gden);
  k_kvl<<<dim3(64, 8), 256, 32768 + 16*136*2, stream>>>(wkvl, gnum, gden, kvl);
  k_klnorm<<<dim3(16, 8, 8), 64, 0, stream>>>(kvl, khat, gvl);
  k_mmat<<<dim3(4, 8, 8), 256, 0, stream>>>(wproj, gvl, Mg);
  k_attn2p2<<<dim3(32, 4, 8), 256, 42496, stream>>>(wqx, xT, khat, Pg);
  k_out<<<dim3(32, 8, 8), 256, 52224, stream>>>(Mg, Pg, biasf, d_out, flag);
}